// Round 1
// baseline (487.116 us; speedup 1.0000x reference)
//
#include <hip/hip_runtime.h>
#include <hip/hip_bf16.h>

typedef unsigned short u16;
typedef __attribute__((ext_vector_type(8))) short bf16x8;
typedef __attribute__((ext_vector_type(4))) float f32x4;

#define LOG2E_F 1.4426950408889634f
// ssmax_scale * log2(e), folded into Q after RoPE
#define QSCALE (0.08838834764831845f * 7.625595228825695f * 1.4426950408889634f)

__device__ __forceinline__ u16 f2bf(float f) {
  unsigned x = __float_as_uint(f);
  unsigned r = (x + 0x7fffu + ((x >> 16) & 1u)) >> 16;  // RNE
  return (u16)r;
}
__device__ __forceinline__ float bf2f(u16 u) {
  return __uint_as_float(((unsigned)u) << 16);
}

__device__ __forceinline__ void gload_lds16(const void* g, void* l) {
  __builtin_amdgcn_global_load_lds(
      (__attribute__((address_space(1))) void*)(g),
      (__attribute__((address_space(3))) void*)(l), 16, 0, 0);
}

__device__ __forceinline__ f32x4 mfma16(bf16x8 a, bf16x8 b, f32x4 c) {
  return __builtin_amdgcn_mfma_f32_16x16x32_bf16(a, b, c, 0, 0, 0);
}

// ---------------- convert x: f32 -> bf16 ----------------
__global__ __launch_bounds__(256) void cvt_x(const float4* __restrict__ x,
                                             ushort4* __restrict__ xb) {
  size_t i = (size_t)blockIdx.x * 256 + threadIdx.x;  // 2,097,152 threads * 4 elems
  float4 v = x[i];
  ushort4 o;
  o.x = f2bf(v.x); o.y = f2bf(v.y); o.z = f2bf(v.z); o.w = f2bf(v.w);
  xb[i] = o;
}

// ------------- transpose+convert W [4096][N] f32 -> Wt [N][4096] bf16 -------------
__global__ __launch_bounds__(256) void tcvt(const float* __restrict__ src,
                                            u16* __restrict__ dst, int N) {
  __shared__ float t[64][65];
  int bid = blockIdx.x;
  int kt = bid & 63, nt = bid >> 6;  // 4096/64 = 64 k-tiles
  int k0 = kt * 64, n0 = nt * 64;
  int tid = threadIdx.x;
#pragma unroll
  for (int it = 0; it < 16; ++it) {
    int idx = it * 256 + tid;
    int row = idx >> 6, col = idx & 63;
    t[row][col] = src[(size_t)(k0 + row) * N + n0 + col];
  }
  __syncthreads();
#pragma unroll
  for (int it = 0; it < 8; ++it) {
    int idx = it * 256 + tid;
    int nrow = idx >> 5, kc = idx & 31;
    ushort2 o;
    o.x = f2bf(t[kc * 2][nrow]);
    o.y = f2bf(t[kc * 2 + 1][nrow]);
    *(ushort2*)&dst[(size_t)(n0 + nrow) * 4096 + k0 + kc * 2] = o;
  }
}

// ---------------- mask flag: nonzero detector ----------------
__global__ __launch_bounds__(256) void maskflag(const float4* __restrict__ mask,
                                                int* __restrict__ flag) {
  size_t i = (size_t)blockIdx.x * 256 + threadIdx.x;  // 1,048,576 threads
  float4 v = mask[i];
  if (v.x != 0.f || v.y != 0.f || v.z != 0.f || v.w != 0.f) atomicOr(flag, 1);
}

// ---------------- trig tables ----------------
__global__ __launch_bounds__(256) void trig_kernel(const int* __restrict__ row_ids,
                                                   const int* __restrict__ col_ids,
                                                   float4* __restrict__ trig) {
  int idx = blockIdx.x * 256 + threadIdx.x;  // 65536 = 2048 tokens * 32 freqs
  int tok = idx >> 5, i = idx & 31;
  // inv_freq = 10000^(-i/32) = exp2(-i * log2(10000)/32)
  float inv = exp2f(-(float)i * 0.41524101186092030f);
  float ar = (float)row_ids[tok] * inv;
  float ac = (float)col_ids[tok] * inv * 1.618033988749895f;
  float4 o;
  o.x = cosf(ar); o.y = sinf(ar); o.z = cosf(ac); o.w = sinf(ac);
  trig[idx] = o;
}

// ---------------- RMSNorm + gg-RoPE (in-place on QK buffer) ----------------
// qk: [2048][5120] bf16 (Q: cols 0..4095, K: cols 4096..5119)
__global__ __launch_bounds__(256) void rope_kernel(u16* __restrict__ qk,
                                                   const float4* __restrict__ trig,
                                                   const float* __restrict__ qw,
                                                   const float* __restrict__ kw) {
  const int tok = blockIdx.x;
  const int tid = threadIdx.x;
  const int w = tid >> 6, lane = tid & 63;
  float4 t4 = trig[tok * 32 + (lane & 31)];
  float sgn = (lane < 32) ? -1.0f : 1.0f;

  for (int it = 0; it < 10; ++it) {
    int hh = w + it * 4;  // 0..39: 32 Q heads then 8 K heads
    bool isQ = (hh < 32);
    int colbase = isQ ? hh * 128 : 4096 + (hh - 32) * 128;
    const float* nw = isQ ? qw : kw;
    float scale = isQ ? QSCALE : 1.0f;
    u16* p = qk + (size_t)tok * 5120 + colbase;
    float v1 = bf2f(p[lane]);        // d = lane       (row-rope half)
    float v2 = bf2f(p[64 + lane]);   // d = 64 + lane  (col-rope half)
    float w1 = nw[lane], w2 = nw[64 + lane];
    float ss = v1 * v1 + v2 * v2;
    ss += __shfl_xor(ss, 1);  ss += __shfl_xor(ss, 2);  ss += __shfl_xor(ss, 4);
    ss += __shfl_xor(ss, 8);  ss += __shfl_xor(ss, 16); ss += __shfl_xor(ss, 32);
    float rinv = rsqrtf(ss * (1.0f / 128.0f) + 1e-6f);
    float n1 = v1 * rinv * w1;
    float n2 = v2 * rinv * w2;
    float p1 = __shfl_xor(n1, 32);
    float p2 = __shfl_xor(n2, 32);
    // d<32: t1*cos - t2*sin ; d>=32: t1*sin + t2*cos
    float r1 = n1 * t4.x + sgn * p1 * t4.y;
    float r2 = n2 * t4.z + sgn * p2 * t4.w;
    p[lane]      = f2bf(r1 * scale);
    p[64 + lane] = f2bf(r2 * scale);
  }
}

// ---------------- GEMM: C[M][N] = A[M][4096] * Bt[N][4096]^T ----------------
// MODE 0: QKV (C->qk bf16 [2048][5120] for n<5120; V transposed -> Vt [1024][2048])
// MODE 1: out-proj (C -> f32 [2048][4096])
template <int MODE>
__global__ __launch_bounds__(256) void gemm128(const u16* __restrict__ A,
                                               const u16* __restrict__ Bt,
                                               void* __restrict__ C0,
                                               u16* __restrict__ Vt, int ntiles) {
  __shared__ u16 a_lds[128 * 64];
  __shared__ u16 b_lds[128 * 64];
  const int tid = threadIdx.x, lane = tid & 63, w = tid >> 6;
  const int l15 = lane & 15, l4 = lane >> 4;
  const int bid = blockIdx.x;
  const int nt = bid % ntiles, mt = bid / ntiles;
  const int m0 = mt * 128, n0 = nt * 128;
  const int wr = w >> 1, wc = w & 1;

  f32x4 acc[4][4];
#pragma unroll
  for (int i = 0; i < 4; ++i)
#pragma unroll
    for (int j = 0; j < 4; ++j) acc[i][j] = (f32x4){0.f, 0.f, 0.f, 0.f};

  const char* Ab = (const char*)A;
  const char* Bb = (const char*)Bt;

  for (int kt = 0; kt < 64; ++kt) {
    __syncthreads();
#pragma unroll
    for (int rd = 0; rd < 4; ++rd) {
      int c = rd * 256 + tid;
      int row = c >> 3;                               // 8 chunks / 128B row
      int kbyte = ((c & 7) * 16) ^ ((row & 7) << 4);  // pre-swizzled source
      gload_lds16(Ab + (size_t)(m0 + row) * 8192 + kt * 128 + kbyte,
                  (char*)a_lds + (rd * 256 + w * 64) * 16);
      gload_lds16(Bb + (size_t)(n0 + row) * 8192 + kt * 128 + kbyte,
                  (char*)b_lds + (rd * 256 + w * 64) * 16);
    }
    __syncthreads();
#pragma unroll
    for (int ks = 0; ks < 2; ++ks) {
      bf16x8 af[4], bfr[4];
      int kbyte = (l4 * 16 + 64 * ks) ^ ((l15 & 7) << 4);
#pragma unroll
      for (int i = 0; i < 4; ++i) {
        int rowa = wr * 64 + i * 16 + l15;
        af[i] = *(const bf16x8*)((const char*)a_lds + rowa * 128 + kbyte);
        int rowb = wc * 64 + i * 16 + l15;
        bfr[i] = *(const bf16x8*)((const char*)b_lds + rowb * 128 + kbyte);
      }
#pragma unroll
      for (int mf = 0; mf < 4; ++mf)
#pragma unroll
        for (int nf = 0; nf < 4; ++nf)
          acc[mf][nf] = mfma16(af[mf], bfr[nf], acc[mf][nf]);
    }
  }

  if (MODE == 0) {
    if (n0 < 5120) {
      u16* qkp = (u16*)C0;
#pragma unroll
      for (int mf = 0; mf < 4; ++mf)
#pragma unroll
        for (int nf = 0; nf < 4; ++nf) {
          int ng = n0 + wc * 64 + nf * 16 + l15;
#pragma unroll
          for (int r = 0; r < 4; ++r) {
            int mg = m0 + wr * 64 + mf * 16 + l4 * 4 + r;
            qkp[(size_t)mg * 5120 + ng] = f2bf(acc[mf][nf][r]);
          }
        }
    } else {
#pragma unroll
      for (int mf = 0; mf < 4; ++mf)
#pragma unroll
        for (int nf = 0; nf < 4; ++nf) {
          int vr = (n0 - 5120) + wc * 64 + nf * 16 + l15;
          int mg = m0 + wr * 64 + mf * 16 + l4 * 4;
          ushort4 pk;
          pk.x = f2bf(acc[mf][nf][0]); pk.y = f2bf(acc[mf][nf][1]);
          pk.z = f2bf(acc[mf][nf][2]); pk.w = f2bf(acc[mf][nf][3]);
          *(ushort4*)&Vt[(size_t)vr * 2048 + mg] = pk;
        }
    }
  } else {
    float* Cp = (float*)C0;
#pragma unroll
    for (int mf = 0; mf < 4; ++mf)
#pragma unroll
      for (int nf = 0; nf < 4; ++nf) {
        int ng = n0 + wc * 64 + nf * 16 + l15;
#pragma unroll
        for (int r = 0; r < 4; ++r) {
          int mg = m0 + wr * 64 + mf * 16 + l4 * 4 + r;
          Cp[(size_t)mg * 4096 + ng] = acc[mf][nf][r];
        }
      }
  }
}

// ---------------- GQA flash attention ----------------
// qk: [2048][5120] bf16 (post-rope, Q pre-scaled by QSCALE)
// vt: [1024][2048] bf16 (V transposed: row = hk*128+d, col = t)
// oat: [2048][4096] bf16
__global__ __launch_bounds__(256) void attn_kernel(const u16* __restrict__ qk,
                                                   const u16* __restrict__ vt,
                                                   u16* __restrict__ oat,
                                                   const float* __restrict__ mask,
                                                   const int* __restrict__ flag) {
  __shared__ u16 k_lds[64 * 128];   // [kv][d], swizzled, 16 slots/row
  __shared__ u16 v_lds[128 * 64];   // [d][kv], swizzled, 8 slots/row
  __shared__ u16 p_lds[4 * 16 * 64];// per-wave [16 q][64 kv], swizzled

  const int tid = threadIdx.x, lane = tid & 63, w = tid >> 6;
  const int l15 = lane & 15, l4 = lane >> 4;
  const int bid = blockIdx.x;
  const int h = bid >> 5;   // q head 0..31
  const int qt = bid & 31;  // q tile 0..31
  const int hk = h >> 2;    // kv head

  // Q fragments (held in registers for the whole block)
  bf16x8 qf[4];
  {
    const char* qp = (const char*)qk + (size_t)(qt * 64 + w * 16 + l15) * 10240 + h * 256;
#pragma unroll
    for (int s = 0; s < 4; ++s) qf[s] = *(const bf16x8*)(qp + l4 * 16 + 64 * s);
  }

  f32x4 oacc[8];
#pragma unroll
  for (int f = 0; f < 8; ++f) oacc[f] = (f32x4){0.f, 0.f, 0.f, 0.f};
  float m_r[4] = {-1e30f, -1e30f, -1e30f, -1e30f};
  float l_r[4] = {0.f, 0.f, 0.f, 0.f};

  const bool use_mask = (*flag != 0);
  const char* kbase = (const char*)qk + 8192 + hk * 256;  // col 4096 + hk*128
  const char* vbase = (const char*)vt + (size_t)hk * 128 * 4096;
  u16* pw = p_lds + w * 1024;

  for (int kt = 0; kt < 32; ++kt) {
    const int kv0 = kt * 64;
    __syncthreads();
    // stage K tile: 64 rows x 256B (16 chunks/row)
#pragma unroll
    for (int rd = 0; rd < 4; ++rd) {
      int c = rd * 256 + tid;
      int row = c >> 4;
      int kbyte = ((c & 15) * 16) ^ ((row & 15) << 4);
      gload_lds16(kbase + (size_t)(kv0 + row) * 10240 + kbyte,
                  (char*)k_lds + (rd * 256 + w * 64) * 16);
    }
    // stage Vt tile: 128 rows x 128B (8 chunks/row)
#pragma unroll
    for (int rd = 0; rd < 4; ++rd) {
      int c = rd * 256 + tid;
      int row = c >> 3;
      int kbyte = ((c & 7) * 16) ^ ((row & 7) << 4);
      gload_lds16(vbase + (size_t)row * 4096 + kv0 * 2 + kbyte,
                  (char*)v_lds + (rd * 256 + w * 64) * 16);
    }
    __syncthreads();

    // S = Q K^T  (rows: wave's 16 q, cols: 64 kv)
    f32x4 s[4];
#pragma unroll
    for (int f = 0; f < 4; ++f) s[f] = (f32x4){0.f, 0.f, 0.f, 0.f};
#pragma unroll
    for (int ks = 0; ks < 4; ++ks) {
#pragma unroll
      for (int f = 0; f < 4; ++f) {
        int row = 16 * f + l15;
        int kbyte = (l4 * 16 + 64 * ks) ^ (l15 << 4);
        bf16x8 kf = *(const bf16x8*)((const char*)k_lds + row * 256 + kbyte);
        s[f] = mfma16(qf[ks], kf, s[f]);
      }
    }

    if (use_mask) {
#pragma unroll
      for (int f = 0; f < 4; ++f)
#pragma unroll
        for (int r = 0; r < 4; ++r) {
          int qg = qt * 64 + w * 16 + l4 * 4 + r;
          int kg = kv0 + 16 * f + l15;
          s[f][r] += LOG2E_F * mask[(size_t)qg * 2048 + kg];
        }
    }

    // online softmax (exp2 domain; scale already folded into Q)
    float mnew[4], alpha[4], psum[4];
#pragma unroll
    for (int r = 0; r < 4; ++r) {
      float mx = fmaxf(fmaxf(s[0][r], s[1][r]), fmaxf(s[2][r], s[3][r]));
      mx = fmaxf(mx, __shfl_xor(mx, 1));
      mx = fmaxf(mx, __shfl_xor(mx, 2));
      mx = fmaxf(mx, __shfl_xor(mx, 4));
      mx = fmaxf(mx, __shfl_xor(mx, 8));
      mnew[r] = fmaxf(m_r[r], mx);
      alpha[r] = exp2f(m_r[r] - mnew[r]);
      m_r[r] = mnew[r];
      psum[r] = 0.f;
    }
#pragma unroll
    for (int f = 0; f < 4; ++f)
#pragma unroll
      for (int r = 0; r < 4; ++r) {
        float p = exp2f(s[f][r] - mnew[r]);
        psum[r] += p;
        int row = l4 * 4 + r;
        int colb = (16 * f + l15) * 2;
        *(u16*)((char*)pw + row * 128 + (colb ^ ((row & 7) << 4))) = f2bf(p);
      }
#pragma unroll
    for (int r = 0; r < 4; ++r) {
      float ps = psum[r];
      ps += __shfl_xor(ps, 1); ps += __shfl_xor(ps, 2);
      ps += __shfl_xor(ps, 4); ps += __shfl_xor(ps, 8);
      l_r[r] = l_r[r] * alpha[r] + ps;
#pragma unroll
      for (int f = 0; f < 8; ++f) oacc[f][r] *= alpha[r];
    }

    // O += P V   (A = P from per-wave LDS, B = Vt)
#pragma unroll
    for (int ks = 0; ks < 2; ++ks) {
      int kbA = (l4 * 16 + 64 * ks) ^ ((l15 & 7) << 4);
      bf16x8 pa = *(const bf16x8*)((const char*)pw + l15 * 128 + kbA);
#pragma unroll
      for (int f = 0; f < 8; ++f) {
        int row = 16 * f + l15;
        int kbB = (l4 * 16 + 64 * ks) ^ ((row & 7) << 4);
        bf16x8 vb = *(const bf16x8*)((const char*)v_lds + row * 128 + kbB);
        oacc[f] = mfma16(pa, vb, oacc[f]);
      }
    }
  }

  // epilogue: normalize and write
#pragma unroll
  for (int f = 0; f < 8; ++f)
#pragma unroll
    for (int r = 0; r < 4; ++r) {
      float o = oacc[f][r] / l_r[r];
      int qg = qt * 64 + w * 16 + l4 * 4 + r;
      int dg = 16 * f + l15;
      oat[(size_t)qg * 4096 + h * 128 + dg] = f2bf(o);
    }
}

// ---------------- launch ----------------
extern "C" void kernel_launch(void* const* d_in, const int* in_sizes, int n_in,
                              void* d_out, int out_size, void* d_ws, size_t ws_size,
                              hipStream_t stream) {
  const float* x = (const float*)d_in[0];
  const int* row_ids = (const int*)d_in[1];
  const int* col_ids = (const int*)d_in[2];
  const float* mask = (const float*)d_in[3];
  const float* Wq = (const float*)d_in[4];
  const float* Wk = (const float*)d_in[5];
  const float* Wv = (const float*)d_in[6];
  const float* Wo = (const float*)d_in[7];
  const float* qw = (const float*)d_in[8];
  const float* kw = (const float*)d_in[9];

  char* ws = (char*)d_ws;
  u16* xb      = (u16*)(ws);                   // 16,777,216 B  x bf16 [2048][4096]
  u16* wqkvt   = (u16*)(ws + 16777216);        // 50,331,648 B  [6144][4096]
  u16* wot     = (u16*)(ws + 67108864);        // 33,554,432 B  [4096][4096]
  u16* qkbuf   = (u16*)(ws + 100663296);       // 20,971,520 B  [2048][5120]
  u16* vtbuf   = (u16*)(ws + 121634816);       //  4,194,304 B  [1024][2048]
  u16* oat     = (u16*)(ws + 125829120);       // 16,777,216 B  [2048][4096]
  float4* trig = (float4*)(ws + 142606336);    //  1,048,576 B
  int* flag    = (int*)(ws + 143654912);       //  4 B

  hipMemsetAsync(flag, 0, 4, stream);
  maskflag<<<4096, 256, 0, stream>>>((const float4*)mask, flag);
  cvt_x<<<8192, 256, 0, stream>>>((const float4*)x, (ushort4*)xb);
  tcvt<<<64 * 64, 256, 0, stream>>>(Wq, wqkvt, 4096);
  tcvt<<<64 * 16, 256, 0, stream>>>(Wk, wqkvt + (size_t)4096 * 4096, 1024);
  tcvt<<<64 * 16, 256, 0, stream>>>(Wv, wqkvt + (size_t)5120 * 4096, 1024);
  tcvt<<<64 * 64, 256, 0, stream>>>(Wo, wot, 4096);
  trig_kernel<<<256, 256, 0, stream>>>(row_ids, col_ids, trig);
  gemm128<0><<<16 * 48, 256, 0, stream>>>(xb, wqkvt, (void*)qkbuf, vtbuf, 48);
  rope_kernel<<<2048, 256, 0, stream>>>(qkbuf, trig, qw, kw);
  attn_kernel<<<1024, 256, 0, stream>>>(qkbuf, vtbuf, oat, mask, flag);
  gemm128<1><<<16 * 32, 256, 0, stream>>>(oat, wot, d_out, nullptr, 32);
}

// Round 2
// 457.945 us; speedup vs baseline: 1.0637x; 1.0637x over previous
//
#include <hip/hip_runtime.h>
#include <hip/hip_bf16.h>

typedef unsigned short u16;
typedef __attribute__((ext_vector_type(8))) short bf16x8;
typedef __attribute__((ext_vector_type(4))) float f32x4;

#define LOG2E_F 1.4426950408889634f
// ssmax_scale * log2(e), folded into Q after RoPE
#define QSCALE (0.08838834764831845f * 7.625595228825695f * 1.4426950408889634f)

__device__ __forceinline__ u16 f2bf(float f) {
  unsigned x = __float_as_uint(f);
  unsigned r = (x + 0x7fffu + ((x >> 16) & 1u)) >> 16;  // RNE
  return (u16)r;
}
__device__ __forceinline__ float bf2f(u16 u) {
  return __uint_as_float(((unsigned)u) << 16);
}
__device__ __forceinline__ float exp2a(float x) {
  float r;
  asm("v_exp_f32 %0, %1" : "=v"(r) : "v"(x));
  return r;
}
__device__ __forceinline__ unsigned cvtpk(float lo, float hi) {
  unsigned r;
  asm("v_cvt_pk_bf16_f32 %0, %1, %2" : "=v"(r) : "v"(lo), "v"(hi));
  return r;
}

__device__ __forceinline__ void gload_lds16(const void* g, void* l) {
  __builtin_amdgcn_global_load_lds(
      (__attribute__((address_space(1))) void*)(g),
      (__attribute__((address_space(3))) void*)(l), 16, 0, 0);
}

__device__ __forceinline__ f32x4 mfma16(bf16x8 a, bf16x8 b, f32x4 c) {
  return __builtin_amdgcn_mfma_f32_16x16x32_bf16(a, b, c, 0, 0, 0);
}

// ---------------- convert x: f32 -> bf16 ----------------
__global__ __launch_bounds__(256) void cvt_x(const float4* __restrict__ x,
                                             ushort4* __restrict__ xb) {
  size_t i = (size_t)blockIdx.x * 256 + threadIdx.x;
  float4 v = x[i];
  ushort4 o;
  o.x = f2bf(v.x); o.y = f2bf(v.y); o.z = f2bf(v.z); o.w = f2bf(v.w);
  xb[i] = o;
}

// ------------- transpose+convert W [4096][N] f32 -> Wt [N][4096] bf16 -------------
__global__ __launch_bounds__(256) void tcvt(const float* __restrict__ src,
                                            u16* __restrict__ dst, int N) {
  __shared__ float t[64][65];
  int bid = blockIdx.x;
  int kt = bid & 63, nt = bid >> 6;
  int k0 = kt * 64, n0 = nt * 64;
  int tid = threadIdx.x;
#pragma unroll
  for (int it = 0; it < 16; ++it) {
    int idx = it * 256 + tid;
    int row = idx >> 6, col = idx & 63;
    t[row][col] = src[(size_t)(k0 + row) * N + n0 + col];
  }
  __syncthreads();
#pragma unroll
  for (int it = 0; it < 8; ++it) {
    int idx = it * 256 + tid;
    int nrow = idx >> 5, kc = idx & 31;
    ushort2 o;
    o.x = f2bf(t[kc * 2][nrow]);
    o.y = f2bf(t[kc * 2 + 1][nrow]);
    *(ushort2*)&dst[(size_t)(n0 + nrow) * 4096 + k0 + kc * 2] = o;
  }
}

// ---------------- mask flag: nonzero detector ----------------
__global__ __launch_bounds__(256) void maskflag(const float4* __restrict__ mask,
                                                int* __restrict__ flag) {
  size_t i = (size_t)blockIdx.x * 256 + threadIdx.x;
  float4 v = mask[i];
  if (v.x != 0.f || v.y != 0.f || v.z != 0.f || v.w != 0.f) atomicOr(flag, 1);
}

// ---------------- trig tables ----------------
__global__ __launch_bounds__(256) void trig_kernel(const int* __restrict__ row_ids,
                                                   const int* __restrict__ col_ids,
                                                   float4* __restrict__ trig) {
  int idx = blockIdx.x * 256 + threadIdx.x;
  int tok = idx >> 5, i = idx & 31;
  float inv = exp2f(-(float)i * 0.41524101186092030f);
  float ar = (float)row_ids[tok] * inv;
  float ac = (float)col_ids[tok] * inv * 1.618033988749895f;
  float4 o;
  o.x = cosf(ar); o.y = sinf(ar); o.z = cosf(ac); o.w = sinf(ac);
  trig[idx] = o;
}

// ---------------- RMSNorm + gg-RoPE (in-place on QK buffer) ----------------
__global__ __launch_bounds__(256) void rope_kernel(u16* __restrict__ qk,
                                                   const float4* __restrict__ trig,
                                                   const float* __restrict__ qw,
                                                   const float* __restrict__ kw) {
  const int tok = blockIdx.x;
  const int tid = threadIdx.x;
  const int w = tid >> 6, lane = tid & 63;
  float4 t4 = trig[tok * 32 + (lane & 31)];
  float sgn = (lane < 32) ? -1.0f : 1.0f;

  for (int it = 0; it < 10; ++it) {
    int hh = w + it * 4;
    bool isQ = (hh < 32);
    int colbase = isQ ? hh * 128 : 4096 + (hh - 32) * 128;
    const float* nw = isQ ? qw : kw;
    float scale = isQ ? QSCALE : 1.0f;
    u16* p = qk + (size_t)tok * 5120 + colbase;
    float v1 = bf2f(p[lane]);
    float v2 = bf2f(p[64 + lane]);
    float w1 = nw[lane], w2 = nw[64 + lane];
    float ss = v1 * v1 + v2 * v2;
    ss += __shfl_xor(ss, 1);  ss += __shfl_xor(ss, 2);  ss += __shfl_xor(ss, 4);
    ss += __shfl_xor(ss, 8);  ss += __shfl_xor(ss, 16); ss += __shfl_xor(ss, 32);
    float rinv = rsqrtf(ss * (1.0f / 128.0f) + 1e-6f);
    float n1 = v1 * rinv * w1;
    float n2 = v2 * rinv * w2;
    float p1 = __shfl_xor(n1, 32);
    float p2 = __shfl_xor(n2, 32);
    float r1 = n1 * t4.x + sgn * p1 * t4.y;
    float r2 = n2 * t4.z + sgn * p2 * t4.w;
    p[lane]      = f2bf(r1 * scale);
    p[64 + lane] = f2bf(r2 * scale);
  }
}

// ---------------- GEMM: C[M][N] = A[M][4096] * Bt[N][4096]^T ----------------
template <int MODE>
__global__ __launch_bounds__(256) void gemm128(const u16* __restrict__ A,
                                               const u16* __restrict__ Bt,
                                               void* __restrict__ C0,
                                               u16* __restrict__ Vt, int ntiles) {
  __shared__ u16 a_lds[128 * 64];
  __shared__ u16 b_lds[128 * 64];
  const int tid = threadIdx.x, lane = tid & 63, w = tid >> 6;
  const int l15 = lane & 15, l4 = lane >> 4;
  const int bid = blockIdx.x;
  const int nt = bid % ntiles, mt = bid / ntiles;
  const int m0 = mt * 128, n0 = nt * 128;
  const int wr = w >> 1, wc = w & 1;

  f32x4 acc[4][4];
#pragma unroll
  for (int i = 0; i < 4; ++i)
#pragma unroll
    for (int j = 0; j < 4; ++j) acc[i][j] = (f32x4){0.f, 0.f, 0.f, 0.f};

  const char* Ab = (const char*)A;
  const char* Bb = (const char*)Bt;

  for (int kt = 0; kt < 64; ++kt) {
    __syncthreads();
#pragma unroll
    for (int rd = 0; rd < 4; ++rd) {
      int c = rd * 256 + tid;
      int row = c >> 3;
      int kbyte = ((c & 7) * 16) ^ ((row & 7) << 4);
      gload_lds16(Ab + (size_t)(m0 + row) * 8192 + kt * 128 + kbyte,
                  (char*)a_lds + (rd * 256 + w * 64) * 16);
      gload_lds16(Bb + (size_t)(n0 + row) * 8192 + kt * 128 + kbyte,
                  (char*)b_lds + (rd * 256 + w * 64) * 16);
    }
    __syncthreads();
#pragma unroll
    for (int ks = 0; ks < 2; ++ks) {
      bf16x8 af[4], bfr[4];
      int kbyte = (l4 * 16 + 64 * ks) ^ ((l15 & 7) << 4);
#pragma unroll
      for (int i = 0; i < 4; ++i) {
        int rowa = wr * 64 + i * 16 + l15;
        af[i] = *(const bf16x8*)((const char*)a_lds + rowa * 128 + kbyte);
        int rowb = wc * 64 + i * 16 + l15;
        bfr[i] = *(const bf16x8*)((const char*)b_lds + rowb * 128 + kbyte);
      }
#pragma unroll
      for (int mf = 0; mf < 4; ++mf)
#pragma unroll
        for (int nf = 0; nf < 4; ++nf)
          acc[mf][nf] = mfma16(af[mf], bfr[nf], acc[mf][nf]);
    }
  }

  if (MODE == 0) {
    if (n0 < 5120) {
      u16* qkp = (u16*)C0;
#pragma unroll
      for (int mf = 0; mf < 4; ++mf)
#pragma unroll
        for (int nf = 0; nf < 4; ++nf) {
          int ng = n0 + wc * 64 + nf * 16 + l15;
#pragma unroll
          for (int r = 0; r < 4; ++r) {
            int mg = m0 + wr * 64 + mf * 16 + l4 * 4 + r;
            qkp[(size_t)mg * 5120 + ng] = f2bf(acc[mf][nf][r]);
          }
        }
    } else {
#pragma unroll
      for (int mf = 0; mf < 4; ++mf)
#pragma unroll
        for (int nf = 0; nf < 4; ++nf) {
          int vr = (n0 - 5120) + wc * 64 + nf * 16 + l15;
          int mg = m0 + wr * 64 + mf * 16 + l4 * 4;
          ushort4 pk;
          pk.x = f2bf(acc[mf][nf][0]); pk.y = f2bf(acc[mf][nf][1]);
          pk.z = f2bf(acc[mf][nf][2]); pk.w = f2bf(acc[mf][nf][3]);
          *(ushort4*)&Vt[(size_t)vr * 2048 + mg] = pk;
        }
    }
  } else {
    float* Cp = (float*)C0;
#pragma unroll
    for (int mf = 0; mf < 4; ++mf)
#pragma unroll
      for (int nf = 0; nf < 4; ++nf) {
        int ng = n0 + wc * 64 + nf * 16 + l15;
#pragma unroll
        for (int r = 0; r < 4; ++r) {
          int mg = m0 + wr * 64 + mf * 16 + l4 * 4 + r;
          Cp[(size_t)mg * 4096 + ng] = acc[mf][nf][r];
        }
      }
  }
}

// ---------------- GQA flash attention (swapped-operand, 32q/wave) ----------------
// qk: [2048][5120] bf16 (post-rope, Q pre-scaled by QSCALE incl. log2e)
// vt: [1024][2048] bf16 (V transposed: row = hk*128+d, col = t)
// oat: [2048][4096] bf16
// block: 4 waves x 32 q = 128 q rows; kv step 64; grid 512 (16 qtiles x 32 heads)
__global__ __launch_bounds__(256) void attn_kernel(const u16* __restrict__ qk,
                                                   const u16* __restrict__ vt,
                                                   u16* __restrict__ oat,
                                                   const float* __restrict__ mask,
                                                   const int* __restrict__ flag) {
  __shared__ u16 k_lds[2][64 * 128];  // [kv][d], 256B rows, chunk-XOR swizzled (row&15)
  __shared__ u16 v_lds[2][64 * 128];  // [d=128][kv=64], 128B rows, swizzled (row&7)
  __shared__ u16 p_lds[4][32 * 64];   // per-wave P [q=32][kv=64], swizzled (row&7)

  const int tid = threadIdx.x, lane = tid & 63, w = tid >> 6;
  const int l15 = lane & 15, l4 = lane >> 4;
  // XCD-clustered mapping: xcd = bid&7 gets heads {x, x+8, x+16, x+24}
  const int bid = blockIdx.x;
  const int xcd = bid & 7, sl = bid >> 3;
  const int h = xcd + 8 * (sl >> 4);
  const int qt = sl & 15;
  const int hk = h >> 2;
  const int qbase = qt * 128 + w * 32;

  const bool use_mask = (*flag != 0);
  const char* kbase = (const char*)qk + 8192 + (size_t)hk * 256;
  const char* vbase = (const char*)vt + (size_t)hk * 128 * 4096;

  // Q fragments: qf[qg][ks], B-operand layout (col=q=l15, k=d)
  bf16x8 qf[2][4];
#pragma unroll
  for (int qg = 0; qg < 2; ++qg) {
    const char* qp = (const char*)qk +
                     (size_t)(qbase + qg * 16 + l15) * 10240 + h * 256 + l4 * 16;
#pragma unroll
    for (int ks = 0; ks < 4; ++ks) qf[qg][ks] = *(const bf16x8*)(qp + ks * 64);
  }

  f32x4 oacc[2][8];
#pragma unroll
  for (int qg = 0; qg < 2; ++qg)
#pragma unroll
    for (int fd = 0; fd < 8; ++fd) oacc[qg][fd] = (f32x4){0.f, 0.f, 0.f, 0.f};
  float m_run[2] = {-1e30f, -1e30f};
  float l_run[2] = {0.f, 0.f};

  // stage one kv-tile (K: 64x256B, V: 128x128B), 4+4 rounds of 256x16B
#define STAGE(buf, kv0)                                                        \
  {                                                                            \
    _Pragma("unroll") for (int rd = 0; rd < 4; ++rd) {                         \
      int c = rd * 256 + tid;                                                  \
      int row = c >> 4;                                                        \
      int src = ((c & 15) ^ (row & 15)) << 4;                                  \
      gload_lds16(kbase + (size_t)((kv0) + row) * 10240 + src,                 \
                  (char*)k_lds[buf] + (rd * 256 + w * 64) * 16);               \
      int rowv = c >> 3;                                                       \
      int srcv = ((c & 7) ^ (rowv & 7)) << 4;                                  \
      gload_lds16(vbase + (size_t)rowv * 4096 + (kv0) * 2 + srcv,              \
                  (char*)v_lds[buf] + (rd * 256 + w * 64) * 16);               \
    }                                                                          \
  }

  STAGE(0, 0);
  __syncthreads();

  for (int kt = 0; kt < 32; ++kt) {
    const int cur = kt & 1;
    const int kv0 = kt * 64;
    if (kt < 31) STAGE(cur ^ 1, kv0 + 64);

    // S^T = K-tile x Q  (D rows = kv, cols = q)
    f32x4 sA[2][4];
#pragma unroll
    for (int qg = 0; qg < 2; ++qg)
#pragma unroll
      for (int f = 0; f < 4; ++f) sA[qg][f] = (f32x4){0.f, 0.f, 0.f, 0.f};

    __builtin_amdgcn_s_setprio(1);
#pragma unroll
    for (int ks = 0; ks < 4; ++ks) {
      bf16x8 kf[4];
#pragma unroll
      for (int f = 0; f < 4; ++f) {
        int row = 16 * f + l15;
        int off = ((4 * ks + l4) ^ l15) << 4;
        kf[f] = *(const bf16x8*)((const char*)k_lds[cur] + row * 256 + off);
      }
#pragma unroll
      for (int f = 0; f < 4; ++f) {
        sA[0][f] = mfma16(kf[f], qf[0][ks], sA[0][f]);
        sA[1][f] = mfma16(kf[f], qf[1][ks], sA[1][f]);
      }
    }
    __builtin_amdgcn_s_setprio(0);

    if (use_mask) {
#pragma unroll
      for (int qg = 0; qg < 2; ++qg) {
        int qglob = qbase + qg * 16 + l15;
#pragma unroll
        for (int f = 0; f < 4; ++f)
#pragma unroll
          for (int r = 0; r < 4; ++r) {
            int kvglob = kv0 + 16 * f + 4 * l4 + r;
            sA[qg][f][r] += LOG2E_F * mask[(size_t)qglob * 2048 + kvglob];
          }
      }
    }

    // online softmax per q-group; q is lane-local (l15), kv in (f, l4, reg)
#pragma unroll
    for (int qg = 0; qg < 2; ++qg) {
      float mx = sA[qg][0][0];
#pragma unroll
      for (int f = 0; f < 4; ++f)
#pragma unroll
        for (int r = 0; r < 4; ++r) mx = fmaxf(mx, sA[qg][f][r]);
      mx = fmaxf(mx, __shfl_xor(mx, 16));
      mx = fmaxf(mx, __shfl_xor(mx, 32));
      if (__any(mx > m_run[qg] + 8.0f)) {  // defer-max: rescale only on growth
        float mnew = fmaxf(m_run[qg], mx);
        float a = exp2a(m_run[qg] - mnew);
        l_run[qg] *= a;
        m_run[qg] = mnew;
        float a0 = __shfl(a, 4 * l4 + 0);
        float a1 = __shfl(a, 4 * l4 + 1);
        float a2 = __shfl(a, 4 * l4 + 2);
        float a3 = __shfl(a, 4 * l4 + 3);
#pragma unroll
        for (int fd = 0; fd < 8; ++fd) {
          oacc[qg][fd][0] *= a0; oacc[qg][fd][1] *= a1;
          oacc[qg][fd][2] *= a2; oacc[qg][fd][3] *= a3;
        }
      }
      float ps = 0.f;
      char* pw = (char*)p_lds[w] + (qg * 16 + l15) * 128;
#pragma unroll
      for (int f = 0; f < 4; ++f) {
        float p0 = exp2a(sA[qg][f][0] - m_run[qg]);
        float p1 = exp2a(sA[qg][f][1] - m_run[qg]);
        float p2 = exp2a(sA[qg][f][2] - m_run[qg]);
        float p3 = exp2a(sA[qg][f][3] - m_run[qg]);
        ps += (p0 + p1) + (p2 + p3);
        uint2 wv;
        wv.x = cvtpk(p0, p1);
        wv.y = cvtpk(p2, p3);
        // lane (l15,l4) holds kv {16f+4*l4 .. +3}: chunk 2f+(l4>>1), byte 8*(l4&1)
        int chunk = 2 * f + (l4 >> 1);
        int off = ((chunk ^ (l15 & 7)) << 4) + 8 * (l4 & 1);
        *(uint2*)(pw + off) = wv;
      }
      ps += __shfl_xor(ps, 16);
      ps += __shfl_xor(ps, 32);
      l_run[qg] += ps;
    }

    // O += P V  (A = P [q][kv] from per-wave LDS, B = Vt [d][kv])
    __builtin_amdgcn_s_setprio(1);
#pragma unroll
    for (int ks = 0; ks < 2; ++ks) {
      int off = ((4 * ks + l4) ^ (l15 & 7)) << 4;
      bf16x8 pa0 = *(const bf16x8*)((const char*)p_lds[w] + l15 * 128 + off);
      bf16x8 pa1 = *(const bf16x8*)((const char*)p_lds[w] + (16 + l15) * 128 + off);
#pragma unroll
      for (int fd = 0; fd < 8; ++fd) {
        int row = 16 * fd + l15;
        bf16x8 vb = *(const bf16x8*)((const char*)v_lds[cur] + row * 128 + off);
        oacc[0][fd] = mfma16(pa0, vb, oacc[0][fd]);
        oacc[1][fd] = mfma16(pa1, vb, oacc[1][fd]);
      }
    }
    __builtin_amdgcn_s_setprio(0);
    __syncthreads();
  }

  // epilogue: broadcast l to C-layout lanes, normalize, write
#pragma unroll
  for (int qg = 0; qg < 2; ++qg) {
    float inv[4];
#pragma unroll
    for (int r = 0; r < 4; ++r) inv[r] = 1.0f / __shfl(l_run[qg], 4 * l4 + r);
#pragma unroll
    for (int fd = 0; fd < 8; ++fd) {
      int dg = h * 128 + 16 * fd + l15;
#pragma unroll
      for (int r = 0; r < 4; ++r) {
        int qrow = qbase + qg * 16 + 4 * l4 + r;
        oat[(size_t)qrow * 4096 + dg] = f2bf(oacc[qg][fd][r] * inv[r]);
      }
    }
  }
#undef STAGE
}

// ---------------- launch ----------------
extern "C" void kernel_launch(void* const* d_in, const int* in_sizes, int n_in,
                              void* d_out, int out_size, void* d_ws, size_t ws_size,
                              hipStream_t stream) {
  const float* x = (const float*)d_in[0];
  const int* row_ids = (const int*)d_in[1];
  const int* col_ids = (const int*)d_in[2];
  const float* mask = (const float*)d_in[3];
  const float* Wq = (const float*)d_in[4];
  const float* Wk = (const float*)d_in[5];
  const float* Wv = (const float*)d_in[6];
  const float* Wo = (const float*)d_in[7];
  const float* qw = (const float*)d_in[8];
  const float* kw = (const float*)d_in[9];

  char* ws = (char*)d_ws;
  u16* xb      = (u16*)(ws);
  u16* wqkvt   = (u16*)(ws + 16777216);
  u16* wot     = (u16*)(ws + 67108864);
  u16* qkbuf   = (u16*)(ws + 100663296);
  u16* vtbuf   = (u16*)(ws + 121634816);
  u16* oat     = (u16*)(ws + 125829120);
  float4* trig = (float4*)(ws + 142606336);
  int* flag    = (int*)(ws + 143654912);

  hipMemsetAsync(flag, 0, 4, stream);
  maskflag<<<4096, 256, 0, stream>>>((const float4*)mask, flag);
  cvt_x<<<8192, 256, 0, stream>>>((const float4*)x, (ushort4*)xb);
  tcvt<<<64 * 64, 256, 0, stream>>>(Wq, wqkvt, 4096);
  tcvt<<<64 * 16, 256, 0, stream>>>(Wk, wqkvt + (size_t)4096 * 4096, 1024);
  tcvt<<<64 * 16, 256, 0, stream>>>(Wv, wqkvt + (size_t)5120 * 4096, 1024);
  tcvt<<<64 * 64, 256, 0, stream>>>(Wo, wot, 4096);
  trig_kernel<<<256, 256, 0, stream>>>(row_ids, col_ids, trig);
  gemm128<0><<<16 * 48, 256, 0, stream>>>(xb, wqkvt, (void*)qkbuf, vtbuf, 48);
  rope_kernel<<<2048, 256, 0, stream>>>(qkbuf, trig, qw, kw);
  attn_kernel<<<512, 256, 0, stream>>>(qkbuf, vtbuf, oat, mask, flag);
  gemm128<1><<<16 * 32, 256, 0, stream>>>(oat, wot, d_out, nullptr, 32);
}

// Round 3
// 429.373 us; speedup vs baseline: 1.1345x; 1.0665x over previous
//
#include <hip/hip_runtime.h>
#include <hip/hip_bf16.h>

typedef unsigned short u16;
typedef __attribute__((ext_vector_type(8))) short bf16x8;
typedef __attribute__((ext_vector_type(4))) float f32x4;

#define LOG2E_F 1.4426950408889634f
#define QSCALE (0.08838834764831845f * 7.625595228825695f * 1.4426950408889634f)

__device__ __forceinline__ u16 f2bf(float f) {
  unsigned x = __float_as_uint(f);
  unsigned r = (x + 0x7fffu + ((x >> 16) & 1u)) >> 16;  // RNE
  return (u16)r;
}
__device__ __forceinline__ float bf2f(u16 u) {
  return __uint_as_float(((unsigned)u) << 16);
}
__device__ __forceinline__ float exp2a(float x) {
  float r;
  asm("v_exp_f32 %0, %1" : "=v"(r) : "v"(x));
  return r;
}
__device__ __forceinline__ unsigned cvtpk(float lo, float hi) {
  unsigned r;
  asm("v_cvt_pk_bf16_f32 %0, %1, %2" : "=v"(r) : "v"(lo), "v"(hi));
  return r;
}

__device__ __forceinline__ void gload_lds16(const void* g, void* l) {
  __builtin_amdgcn_global_load_lds(
      (__attribute__((address_space(1))) void*)(g),
      (__attribute__((address_space(3))) void*)(l), 16, 0, 0);
}

__device__ __forceinline__ f32x4 mfma16(bf16x8 a, bf16x8 b, f32x4 c) {
  return __builtin_amdgcn_mfma_f32_16x16x32_bf16(a, b, c, 0, 0, 0);
}

// ---------------- convert x: f32 -> bf16 ----------------
__global__ __launch_bounds__(256) void cvt_x(const float4* __restrict__ x,
                                             ushort4* __restrict__ xb) {
  size_t i = (size_t)blockIdx.x * 256 + threadIdx.x;
  float4 v = x[i];
  ushort4 o;
  o.x = f2bf(v.x); o.y = f2bf(v.y); o.z = f2bf(v.z); o.w = f2bf(v.w);
  xb[i] = o;
}

// ------------- transpose+convert W [4096][N] f32 -> Wt [N][4096] bf16 -------------
__global__ __launch_bounds__(256) void tcvt(const float* __restrict__ src,
                                            u16* __restrict__ dst, int N) {
  __shared__ float t[64][65];
  int bid = blockIdx.x;
  int kt = bid & 63, nt = bid >> 6;
  int k0 = kt * 64, n0 = nt * 64;
  int tid = threadIdx.x;
#pragma unroll
  for (int it = 0; it < 16; ++it) {
    int idx = it * 256 + tid;
    int row = idx >> 6, col = idx & 63;
    t[row][col] = src[(size_t)(k0 + row) * N + n0 + col];
  }
  __syncthreads();
#pragma unroll
  for (int it = 0; it < 8; ++it) {
    int idx = it * 256 + tid;
    int nrow = idx >> 5, kc = idx & 31;
    ushort2 o;
    o.x = f2bf(t[kc * 2][nrow]);
    o.y = f2bf(t[kc * 2 + 1][nrow]);
    *(ushort2*)&dst[(size_t)(n0 + nrow) * 4096 + k0 + kc * 2] = o;
  }
}

// ---------------- mask flag: nonzero detector ----------------
__global__ __launch_bounds__(256) void maskflag(const float4* __restrict__ mask,
                                                int* __restrict__ flag) {
  size_t i = (size_t)blockIdx.x * 256 + threadIdx.x;
  float4 v = mask[i];
  if (v.x != 0.f || v.y != 0.f || v.z != 0.f || v.w != 0.f) atomicOr(flag, 1);
}

// ---------------- trig tables ----------------
__global__ __launch_bounds__(256) void trig_kernel(const int* __restrict__ row_ids,
                                                   const int* __restrict__ col_ids,
                                                   float4* __restrict__ trig) {
  int idx = blockIdx.x * 256 + threadIdx.x;
  int tok = idx >> 5, i = idx & 31;
  float inv = exp2f(-(float)i * 0.41524101186092030f);
  float ar = (float)row_ids[tok] * inv;
  float ac = (float)col_ids[tok] * inv * 1.618033988749895f;
  float4 o;
  o.x = cosf(ar); o.y = sinf(ar); o.z = cosf(ac); o.w = sinf(ac);
  trig[idx] = o;
}

// ---------------- RMSNorm + gg-RoPE (in-place on QK buffer) ----------------
__global__ __launch_bounds__(256) void rope_kernel(u16* __restrict__ qk,
                                                   const float4* __restrict__ trig,
                                                   const float* __restrict__ qw,
                                                   const float* __restrict__ kw) {
  const int tok = blockIdx.x;
  const int tid = threadIdx.x;
  const int w = tid >> 6, lane = tid & 63;
  float4 t4 = trig[tok * 32 + (lane & 31)];
  float sgn = (lane < 32) ? -1.0f : 1.0f;

  for (int it = 0; it < 10; ++it) {
    int hh = w + it * 4;
    bool isQ = (hh < 32);
    int colbase = isQ ? hh * 128 : 4096 + (hh - 32) * 128;
    const float* nw = isQ ? qw : kw;
    float scale = isQ ? QSCALE : 1.0f;
    u16* p = qk + (size_t)tok * 5120 + colbase;
    float v1 = bf2f(p[lane]);
    float v2 = bf2f(p[64 + lane]);
    float w1 = nw[lane], w2 = nw[64 + lane];
    float ss = v1 * v1 + v2 * v2;
    ss += __shfl_xor(ss, 1);  ss += __shfl_xor(ss, 2);  ss += __shfl_xor(ss, 4);
    ss += __shfl_xor(ss, 8);  ss += __shfl_xor(ss, 16); ss += __shfl_xor(ss, 32);
    float rinv = rsqrtf(ss * (1.0f / 128.0f) + 1e-6f);
    float n1 = v1 * rinv * w1;
    float n2 = v2 * rinv * w2;
    float p1 = __shfl_xor(n1, 32);
    float p2 = __shfl_xor(n2, 32);
    float r1 = n1 * t4.x + sgn * p1 * t4.y;
    float r2 = n2 * t4.z + sgn * p2 * t4.w;
    p[lane]      = f2bf(r1 * scale);
    p[64 + lane] = f2bf(r2 * scale);
  }
}

// ======== 256x256 8-phase GEMM: C[M][N] = A[M][4096] * Bt[N][4096]^T ========
// 512 threads = 8 waves (2M x 4N); per-wave 128x64 output; BK=64, 2 K-tiles/iter.
// LDS (dynamic, 128KB): A[slot][half][128][64] @0, B[slot][half][128][64] @64KB.
// Chunk-XOR swizzle: phys_chunk = chunk ^ (row&7) (verified conflict-free).
// MODE 0: QKV -> qk bf16 [2048][5120] (n<5120) / Vt [1024][2048] (n>=5120)
// MODE 1: out-proj -> f32 [2048][4096]
template <int MODE>
__global__ __launch_bounds__(512, 2) void gemm256(const u16* __restrict__ A,
                                                  const u16* __restrict__ Bt,
                                                  void* __restrict__ C0,
                                                  u16* __restrict__ Vt, int nnt) {
  extern __shared__ char smem[];  // [0,64K): A ; [64K,128K): B
  const int tid = threadIdx.x, lane = tid & 63, w = tid >> 6;
  const int l15 = lane & 15, l4 = lane >> 4;
  const int wr = w >> 2, wc = w & 3;

  // XCD-aware swizzle (gridDim %8 == 0): each XCD owns contiguous wgid chunk
  const int grid = gridDim.x;
  const int wgid = (blockIdx.x & 7) * (grid >> 3) + (blockIdx.x >> 3);
  const int mt = wgid / nnt, nt = wgid % nnt;
  const int m0 = mt * 256, n0 = nt * 256;

  // staging address precompute (source pre-inverse-swizzled; LDS dest linear)
  const int kswz = (((tid & 7) ^ ((tid >> 3) & 7)) << 4);
  const char* arow = (const char*)A + (size_t)(m0 + (tid >> 3)) * 8192 + kswz;
  const char* brow = (const char*)Bt + (size_t)(n0 + (tid >> 3)) * 8192 + kswz;

  auto stageA = [&](int t, int h) {
#pragma unroll
    for (int rd = 0; rd < 2; ++rd)
      gload_lds16(arow + (size_t)(h * 128 + rd * 64) * 8192 + t * 128,
                  smem + ((t & 1) * 2 + h) * 16384 + rd * 8192 + w * 1024);
  };
  auto stageB = [&](int t, int h) {
#pragma unroll
    for (int rd = 0; rd < 2; ++rd)
      gload_lds16(brow + (size_t)(h * 128 + rd * 64) * 8192 + t * 128,
                  smem + 65536 + ((t & 1) * 2 + h) * 16384 + rd * 8192 + w * 1024);
  };

  f32x4 acc[8][4];
#pragma unroll
  for (int i = 0; i < 8; ++i)
#pragma unroll
    for (int j = 0; j < 4; ++j) acc[i][j] = (f32x4){0.f, 0.f, 0.f, 0.f};

  const int aoff0 = ((l4) ^ (l15 & 7)) << 4;       // ks=0 chunk
  const int aoff1 = ((4 + l4) ^ (l15 & 7)) << 4;   // ks=1 chunk

  // prologue: A(0), B(0), B(1); drain A(0)+B(0), leave B(1) in flight
  stageA(0, 0); stageA(0, 1);
  stageB(0, 0); stageB(0, 1);
  stageB(1, 0); stageB(1, 1);
  asm volatile("s_waitcnt vmcnt(4)" ::: "memory");
  __builtin_amdgcn_s_barrier();

  auto do_iter = [&](int t0, int last) {
    bf16x8 bfr[4][2];
#pragma unroll
    for (int p = 0; p < 8; ++p) {
      const int s = p >> 2, qd = p & 3;
      // --- ds-load register subtile ---
      const char* aT = smem + (s * 2 + wr) * 16384 + l15 * 128;
      bf16x8 afr[2][2];
#pragma unroll
      for (int jm = 0; jm < 2; ++jm) {
        afr[jm][0] = *(const bf16x8*)(aT + (2 * qd + jm) * 2048 + aoff0);
        afr[jm][1] = *(const bf16x8*)(aT + (2 * qd + jm) * 2048 + aoff1);
      }
      if (qd == 0) {
        const char* bT = smem + 65536 + (s * 2 + (wc >> 1)) * 16384 +
                         ((wc & 1) * 64 + l15) * 128;
#pragma unroll
        for (int nf = 0; nf < 4; ++nf) {
          bfr[nf][0] = *(const bf16x8*)(bT + nf * 2048 + aoff0);
          bfr[nf][1] = *(const bf16x8*)(bT + nf * 2048 + aoff1);
        }
      }
      // --- stage prefetch (region-free windows) ---
      if (p == 0) { stageA(t0 + 1, 0); stageA(t0 + 1, 1); }
      if (!last) {
        if (p == 1) stageB(t0 + 2, 0);
        if (p == 2) stageB(t0 + 2, 1);
        if (p == 4) { stageA(t0 + 2, 0); stageA(t0 + 2, 1); }
        if (p == 5) stageB(t0 + 3, 0);
        if (p == 6) stageB(t0 + 3, 1);
      }
      // --- counted vmcnt at half-iter boundaries ---
      if (p == 3) {
        if (last) asm volatile("s_waitcnt vmcnt(0)" ::: "memory");
        else      asm volatile("s_waitcnt vmcnt(4)" ::: "memory");
      }
      if (p == 7 && !last) asm volatile("s_waitcnt vmcnt(4)" ::: "memory");
      __builtin_amdgcn_s_barrier();
      asm volatile("s_waitcnt lgkmcnt(0)" ::: "memory");
      __builtin_amdgcn_sched_barrier(0);
      __builtin_amdgcn_s_setprio(1);
#pragma unroll
      for (int ks = 0; ks < 2; ++ks)
#pragma unroll
        for (int jm = 0; jm < 2; ++jm)
#pragma unroll
          for (int nf = 0; nf < 4; ++nf)
            acc[2 * qd + jm][nf] =
                mfma16(afr[jm][ks], bfr[nf][ks], acc[2 * qd + jm][nf]);
      __builtin_amdgcn_s_setprio(0);
      __builtin_amdgcn_s_barrier();
    }
  };

  for (int j = 0; j < 31; ++j) do_iter(2 * j, 0);
  do_iter(62, 1);

  // ---- epilogue ----
  if (MODE == 0) {
    if (n0 < 5120) {
      u16* qkp = (u16*)C0;
#pragma unroll
      for (int mf = 0; mf < 8; ++mf)
#pragma unroll
        for (int nf = 0; nf < 4; ++nf) {
          int ng = n0 + wc * 64 + nf * 16 + l15;
#pragma unroll
          for (int r = 0; r < 4; ++r) {
            int mg = m0 + wr * 128 + mf * 16 + l4 * 4 + r;
            qkp[(size_t)mg * 5120 + ng] = f2bf(acc[mf][nf][r]);
          }
        }
    } else {
#pragma unroll
      for (int mf = 0; mf < 8; ++mf)
#pragma unroll
        for (int nf = 0; nf < 4; ++nf) {
          int vr = (n0 - 5120) + wc * 64 + nf * 16 + l15;
          int mg = m0 + wr * 128 + mf * 16 + l4 * 4;
          ushort4 pk;
          pk.x = f2bf(acc[mf][nf][0]); pk.y = f2bf(acc[mf][nf][1]);
          pk.z = f2bf(acc[mf][nf][2]); pk.w = f2bf(acc[mf][nf][3]);
          *(ushort4*)&Vt[(size_t)vr * 2048 + mg] = pk;
        }
    }
  } else {
    float* Cp = (float*)C0;
#pragma unroll
    for (int mf = 0; mf < 8; ++mf)
#pragma unroll
      for (int nf = 0; nf < 4; ++nf) {
        int ng = n0 + wc * 64 + nf * 16 + l15;
#pragma unroll
        for (int r = 0; r < 4; ++r) {
          int mg = m0 + wr * 128 + mf * 16 + l4 * 4 + r;
          Cp[(size_t)mg * 4096 + ng] = acc[mf][nf][r];
        }
      }
  }
}

// ---------------- GQA flash attention (swapped-operand, 32q/wave) ----------------
__global__ __launch_bounds__(256) void attn_kernel(const u16* __restrict__ qk,
                                                   const u16* __restrict__ vt,
                                                   u16* __restrict__ oat,
                                                   const float* __restrict__ mask,
                                                   const int* __restrict__ flag) {
  __shared__ u16 k_lds[2][64 * 128];
  __shared__ u16 v_lds[2][64 * 128];
  __shared__ u16 p_lds[4][32 * 64];

  const int tid = threadIdx.x, lane = tid & 63, w = tid >> 6;
  const int l15 = lane & 15, l4 = lane >> 4;
  const int bid = blockIdx.x;
  const int xcd = bid & 7, sl = bid >> 3;
  const int h = xcd + 8 * (sl >> 4);
  const int qt = sl & 15;
  const int hk = h >> 2;
  const int qbase = qt * 128 + w * 32;

  const bool use_mask = (*flag != 0);
  const char* kbase = (const char*)qk + 8192 + (size_t)hk * 256;
  const char* vbase = (const char*)vt + (size_t)hk * 128 * 4096;

  bf16x8 qf[2][4];
#pragma unroll
  for (int qg = 0; qg < 2; ++qg) {
    const char* qp = (const char*)qk +
                     (size_t)(qbase + qg * 16 + l15) * 10240 + h * 256 + l4 * 16;
#pragma unroll
    for (int ks = 0; ks < 4; ++ks) qf[qg][ks] = *(const bf16x8*)(qp + ks * 64);
  }

  f32x4 oacc[2][8];
#pragma unroll
  for (int qg = 0; qg < 2; ++qg)
#pragma unroll
    for (int fd = 0; fd < 8; ++fd) oacc[qg][fd] = (f32x4){0.f, 0.f, 0.f, 0.f};
  float m_run[2] = {-1e30f, -1e30f};
  float l_run[2] = {0.f, 0.f};

#define STAGE(buf, kv0)                                                        \
  {                                                                            \
    _Pragma("unroll") for (int rd = 0; rd < 4; ++rd) {                         \
      int c = rd * 256 + tid;                                                  \
      int row = c >> 4;                                                        \
      int src = ((c & 15) ^ (row & 15)) << 4;                                  \
      gload_lds16(kbase + (size_t)((kv0) + row) * 10240 + src,                 \
                  (char*)k_lds[buf] + (rd * 256 + w * 64) * 16);               \
      int rowv = c >> 3;                                                       \
      int srcv = ((c & 7) ^ (rowv & 7)) << 4;                                  \
      gload_lds16(vbase + (size_t)rowv * 4096 + (kv0) * 2 + srcv,              \
                  (char*)v_lds[buf] + (rd * 256 + w * 64) * 16);               \
    }                                                                          \
  }

  STAGE(0, 0);
  __syncthreads();

  for (int kt = 0; kt < 32; ++kt) {
    const int cur = kt & 1;
    const int kv0 = kt * 64;
    if (kt < 31) STAGE(cur ^ 1, kv0 + 64);

    f32x4 sA[2][4];
#pragma unroll
    for (int qg = 0; qg < 2; ++qg)
#pragma unroll
      for (int f = 0; f < 4; ++f) sA[qg][f] = (f32x4){0.f, 0.f, 0.f, 0.f};

    __builtin_amdgcn_s_setprio(1);
#pragma unroll
    for (int ks = 0; ks < 4; ++ks) {
      bf16x8 kf[4];
#pragma unroll
      for (int f = 0; f < 4; ++f) {
        int row = 16 * f + l15;
        int off = ((4 * ks + l4) ^ l15) << 4;
        kf[f] = *(const bf16x8*)((const char*)k_lds[cur] + row * 256 + off);
      }
#pragma unroll
      for (int f = 0; f < 4; ++f) {
        sA[0][f] = mfma16(kf[f], qf[0][ks], sA[0][f]);
        sA[1][f] = mfma16(kf[f], qf[1][ks], sA[1][f]);
      }
    }
    __builtin_amdgcn_s_setprio(0);

    if (use_mask) {
#pragma unroll
      for (int qg = 0; qg < 2; ++qg) {
        int qglob = qbase + qg * 16 + l15;
#pragma unroll
        for (int f = 0; f < 4; ++f)
#pragma unroll
          for (int r = 0; r < 4; ++r) {
            int kvglob = kv0 + 16 * f + 4 * l4 + r;
            sA[qg][f][r] += LOG2E_F * mask[(size_t)qglob * 2048 + kvglob];
          }
      }
    }

#pragma unroll
    for (int qg = 0; qg < 2; ++qg) {
      float mx = sA[qg][0][0];
#pragma unroll
      for (int f = 0; f < 4; ++f)
#pragma unroll
        for (int r = 0; r < 4; ++r) mx = fmaxf(mx, sA[qg][f][r]);
      mx = fmaxf(mx, __shfl_xor(mx, 16));
      mx = fmaxf(mx, __shfl_xor(mx, 32));
      if (__any(mx > m_run[qg] + 8.0f)) {
        float mnew = fmaxf(m_run[qg], mx);
        float a = exp2a(m_run[qg] - mnew);
        l_run[qg] *= a;
        m_run[qg] = mnew;
        float a0 = __shfl(a, 4 * l4 + 0);
        float a1 = __shfl(a, 4 * l4 + 1);
        float a2 = __shfl(a, 4 * l4 + 2);
        float a3 = __shfl(a, 4 * l4 + 3);
#pragma unroll
        for (int fd = 0; fd < 8; ++fd) {
          oacc[qg][fd][0] *= a0; oacc[qg][fd][1] *= a1;
          oacc[qg][fd][2] *= a2; oacc[qg][fd][3] *= a3;
        }
      }
      float ps = 0.f;
      char* pw = (char*)p_lds[w] + (qg * 16 + l15) * 128;
#pragma unroll
      for (int f = 0; f < 4; ++f) {
        float p0 = exp2a(sA[qg][f][0] - m_run[qg]);
        float p1 = exp2a(sA[qg][f][1] - m_run[qg]);
        float p2 = exp2a(sA[qg][f][2] - m_run[qg]);
        float p3 = exp2a(sA[qg][f][3] - m_run[qg]);
        ps += (p0 + p1) + (p2 + p3);
        uint2 wv;
        wv.x = cvtpk(p0, p1);
        wv.y = cvtpk(p2, p3);
        int chunk = 2 * f + (l4 >> 1);
        int off = ((chunk ^ (l15 & 7)) << 4) + 8 * (l4 & 1);
        *(uint2*)(pw + off) = wv;
      }
      ps += __shfl_xor(ps, 16);
      ps += __shfl_xor(ps, 32);
      l_run[qg] += ps;
    }

    __builtin_amdgcn_s_setprio(1);
#pragma unroll
    for (int ks = 0; ks < 2; ++ks) {
      int off = ((4 * ks + l4) ^ (l15 & 7)) << 4;
      bf16x8 pa0 = *(const bf16x8*)((const char*)p_lds[w] + l15 * 128 + off);
      bf16x8 pa1 = *(const bf16x8*)((const char*)p_lds[w] + (16 + l15) * 128 + off);
#pragma unroll
      for (int fd = 0; fd < 8; ++fd) {
        int row = 16 * fd + l15;
        bf16x8 vb = *(const bf16x8*)((const char*)v_lds[cur] + row * 128 + off);
        oacc[0][fd] = mfma16(pa0, vb, oacc[0][fd]);
        oacc[1][fd] = mfma16(pa1, vb, oacc[1][fd]);
      }
    }
    __builtin_amdgcn_s_setprio(0);
    __syncthreads();
  }

#pragma unroll
  for (int qg = 0; qg < 2; ++qg) {
    float inv[4];
#pragma unroll
    for (int r = 0; r < 4; ++r) inv[r] = 1.0f / __shfl(l_run[qg], 4 * l4 + r);
#pragma unroll
    for (int fd = 0; fd < 8; ++fd) {
      int dg = h * 128 + 16 * fd + l15;
#pragma unroll
      for (int r = 0; r < 4; ++r) {
        int qrow = qbase + qg * 16 + 4 * l4 + r;
        oat[(size_t)qrow * 4096 + dg] = f2bf(oacc[qg][fd][r] * inv[r]);
      }
    }
  }
#undef STAGE
}

// ---------------- launch ----------------
extern "C" void kernel_launch(void* const* d_in, const int* in_sizes, int n_in,
                              void* d_out, int out_size, void* d_ws, size_t ws_size,
                              hipStream_t stream) {
  const float* x = (const float*)d_in[0];
  const int* row_ids = (const int*)d_in[1];
  const int* col_ids = (const int*)d_in[2];
  const float* mask = (const float*)d_in[3];
  const float* Wq = (const float*)d_in[4];
  const float* Wk = (const float*)d_in[5];
  const float* Wv = (const float*)d_in[6];
  const float* Wo = (const float*)d_in[7];
  const float* qw = (const float*)d_in[8];
  const float* kw = (const float*)d_in[9];

  char* ws = (char*)d_ws;
  u16* xb      = (u16*)(ws);
  u16* wqkvt   = (u16*)(ws + 16777216);
  u16* wot     = (u16*)(ws + 67108864);
  u16* qkbuf   = (u16*)(ws + 100663296);
  u16* vtbuf   = (u16*)(ws + 121634816);
  u16* oat     = (u16*)(ws + 125829120);
  float4* trig = (float4*)(ws + 142606336);
  int* flag    = (int*)(ws + 143654912);

  hipFuncSetAttribute((const void*)gemm256<0>,
                      hipFuncAttributeMaxDynamicSharedMemorySize, 131072);
  hipFuncSetAttribute((const void*)gemm256<1>,
                      hipFuncAttributeMaxDynamicSharedMemorySize, 131072);

  hipMemsetAsync(flag, 0, 4, stream);
  maskflag<<<4096, 256, 0, stream>>>((const float4*)mask, flag);
  cvt_x<<<8192, 256, 0, stream>>>((const float4*)x, (ushort4*)xb);
  tcvt<<<64 * 64, 256, 0, stream>>>(Wq, wqkvt, 4096);
  tcvt<<<64 * 16, 256, 0, stream>>>(Wk, wqkvt + (size_t)4096 * 4096, 1024);
  tcvt<<<64 * 16, 256, 0, stream>>>(Wv, wqkvt + (size_t)5120 * 4096, 1024);
  tcvt<<<64 * 64, 256, 0, stream>>>(Wo, wot, 4096);
  trig_kernel<<<256, 256, 0, stream>>>(row_ids, col_ids, trig);
  gemm256<0><<<192, 512, 131072, stream>>>(xb, wqkvt, (void*)qkbuf, vtbuf, 24);
  rope_kernel<<<2048, 256, 0, stream>>>(qkbuf, trig, qw, kw);
  attn_kernel<<<512, 256, 0, stream>>>(qkbuf, vtbuf, oat, mask, flag);
  gemm256<1><<<128, 512, 131072, stream>>>(oat, wot, d_out, nullptr, 16);
}

// Round 4
// 423.932 us; speedup vs baseline: 1.1490x; 1.0128x over previous
//
#include <hip/hip_runtime.h>
#include <hip/hip_bf16.h>

typedef unsigned short u16;
typedef __attribute__((ext_vector_type(8))) short bf16x8;
typedef __attribute__((ext_vector_type(4))) float f32x4;

#define LOG2E_F 1.4426950408889634f
#define QSCALE (0.08838834764831845f * 7.625595228825695f * 1.4426950408889634f)

__device__ __forceinline__ u16 f2bf(float f) {
  unsigned x = __float_as_uint(f);
  unsigned r = (x + 0x7fffu + ((x >> 16) & 1u)) >> 16;  // RNE
  return (u16)r;
}
__device__ __forceinline__ float bf2f(u16 u) {
  return __uint_as_float(((unsigned)u) << 16);
}
__device__ __forceinline__ float exp2a(float x) {
  float r;
  asm("v_exp_f32 %0, %1" : "=v"(r) : "v"(x));
  return r;
}
__device__ __forceinline__ unsigned cvtpk(float lo, float hi) {
  unsigned r;
  asm("v_cvt_pk_bf16_f32 %0, %1, %2" : "=v"(r) : "v"(lo), "v"(hi));
  return r;
}

__device__ __forceinline__ void gload_lds16(const void* g, void* l) {
  __builtin_amdgcn_global_load_lds(
      (__attribute__((address_space(1))) void*)(g),
      (__attribute__((address_space(3))) void*)(l), 16, 0, 0);
}

__device__ __forceinline__ f32x4 mfma16(bf16x8 a, bf16x8 b, f32x4 c) {
  return __builtin_amdgcn_mfma_f32_16x16x32_bf16(a, b, c, 0, 0, 0);
}

// ---------------- convert x: f32 -> bf16 ----------------
__global__ __launch_bounds__(256) void cvt_x(const float4* __restrict__ x,
                                             ushort4* __restrict__ xb) {
  size_t i = (size_t)blockIdx.x * 256 + threadIdx.x;
  float4 v = x[i];
  ushort4 o;
  o.x = f2bf(v.x); o.y = f2bf(v.y); o.z = f2bf(v.z); o.w = f2bf(v.w);
  xb[i] = o;
}

// ------------- transpose+convert W [4096][N] f32 -> Wt [N][4096] bf16 -------------
__global__ __launch_bounds__(256) void tcvt(const float* __restrict__ src,
                                            u16* __restrict__ dst, int N) {
  __shared__ float t[64][65];
  int bid = blockIdx.x;
  int kt = bid & 63, nt = bid >> 6;
  int k0 = kt * 64, n0 = nt * 64;
  int tid = threadIdx.x;
#pragma unroll
  for (int it = 0; it < 16; ++it) {
    int idx = it * 256 + tid;
    int row = idx >> 6, col = idx & 63;
    t[row][col] = src[(size_t)(k0 + row) * N + n0 + col];
  }
  __syncthreads();
#pragma unroll
  for (int it = 0; it < 8; ++it) {
    int idx = it * 256 + tid;
    int nrow = idx >> 5, kc = idx & 31;
    ushort2 o;
    o.x = f2bf(t[kc * 2][nrow]);
    o.y = f2bf(t[kc * 2 + 1][nrow]);
    *(ushort2*)&dst[(size_t)(n0 + nrow) * 4096 + k0 + kc * 2] = o;
  }
}

// ---------------- mask flag: nonzero detector ----------------
__global__ __launch_bounds__(256) void maskflag(const float4* __restrict__ mask,
                                                int* __restrict__ flag) {
  size_t i = (size_t)blockIdx.x * 256 + threadIdx.x;
  float4 v = mask[i];
  if (v.x != 0.f || v.y != 0.f || v.z != 0.f || v.w != 0.f) atomicOr(flag, 1);
}

// ---------------- trig tables ----------------
__global__ __launch_bounds__(256) void trig_kernel(const int* __restrict__ row_ids,
                                                   const int* __restrict__ col_ids,
                                                   float4* __restrict__ trig) {
  int idx = blockIdx.x * 256 + threadIdx.x;
  int tok = idx >> 5, i = idx & 31;
  float inv = exp2f(-(float)i * 0.41524101186092030f);
  float ar = (float)row_ids[tok] * inv;
  float ac = (float)col_ids[tok] * inv * 1.618033988749895f;
  float4 o;
  o.x = cosf(ar); o.y = sinf(ar); o.z = cosf(ac); o.w = sinf(ac);
  trig[idx] = o;
}

// ---------------- RMSNorm + gg-RoPE (in-place on QK buffer) ----------------
__global__ __launch_bounds__(256) void rope_kernel(u16* __restrict__ qk,
                                                   const float4* __restrict__ trig,
                                                   const float* __restrict__ qw,
                                                   const float* __restrict__ kw) {
  const int tok = blockIdx.x;
  const int tid = threadIdx.x;
  const int w = tid >> 6, lane = tid & 63;
  float4 t4 = trig[tok * 32 + (lane & 31)];
  float sgn = (lane < 32) ? -1.0f : 1.0f;

  for (int it = 0; it < 10; ++it) {
    int hh = w + it * 4;
    bool isQ = (hh < 32);
    int colbase = isQ ? hh * 128 : 4096 + (hh - 32) * 128;
    const float* nw = isQ ? qw : kw;
    float scale = isQ ? QSCALE : 1.0f;
    u16* p = qk + (size_t)tok * 5120 + colbase;
    float v1 = bf2f(p[lane]);
    float v2 = bf2f(p[64 + lane]);
    float w1 = nw[lane], w2 = nw[64 + lane];
    float ss = v1 * v1 + v2 * v2;
    ss += __shfl_xor(ss, 1);  ss += __shfl_xor(ss, 2);  ss += __shfl_xor(ss, 4);
    ss += __shfl_xor(ss, 8);  ss += __shfl_xor(ss, 16); ss += __shfl_xor(ss, 32);
    float rinv = rsqrtf(ss * (1.0f / 128.0f) + 1e-6f);
    float n1 = v1 * rinv * w1;
    float n2 = v2 * rinv * w2;
    float p1 = __shfl_xor(n1, 32);
    float p2 = __shfl_xor(n2, 32);
    float r1 = n1 * t4.x + sgn * p1 * t4.y;
    float r2 = n2 * t4.z + sgn * p2 * t4.w;
    p[lane]      = f2bf(r1 * scale);
    p[64 + lane] = f2bf(r2 * scale);
  }
}

// ======== 256x256 8-phase GEMM: C[M][N] = A[M][4096] * Bt[N][4096]^T ========
template <int MODE>
__global__ __launch_bounds__(512, 2) void gemm256(const u16* __restrict__ A,
                                                  const u16* __restrict__ Bt,
                                                  void* __restrict__ C0,
                                                  u16* __restrict__ Vt, int nnt) {
  extern __shared__ char smem[];  // [0,64K): A ; [64K,128K): B
  const int tid = threadIdx.x, lane = tid & 63, w = tid >> 6;
  const int l15 = lane & 15, l4 = lane >> 4;
  const int wr = w >> 2, wc = w & 3;

  const int grid = gridDim.x;
  const int wgid = (blockIdx.x & 7) * (grid >> 3) + (blockIdx.x >> 3);
  const int mt = wgid / nnt, nt = wgid % nnt;
  const int m0 = mt * 256, n0 = nt * 256;

  const int kswz = (((tid & 7) ^ ((tid >> 3) & 7)) << 4);
  const char* arow = (const char*)A + (size_t)(m0 + (tid >> 3)) * 8192 + kswz;
  const char* brow = (const char*)Bt + (size_t)(n0 + (tid >> 3)) * 8192 + kswz;

  auto stageA = [&](int t, int h) {
#pragma unroll
    for (int rd = 0; rd < 2; ++rd)
      gload_lds16(arow + (size_t)(h * 128 + rd * 64) * 8192 + t * 128,
                  smem + ((t & 1) * 2 + h) * 16384 + rd * 8192 + w * 1024);
  };
  auto stageB = [&](int t, int h) {
#pragma unroll
    for (int rd = 0; rd < 2; ++rd)
      gload_lds16(brow + (size_t)(h * 128 + rd * 64) * 8192 + t * 128,
                  smem + 65536 + ((t & 1) * 2 + h) * 16384 + rd * 8192 + w * 1024);
  };

  f32x4 acc[8][4];
#pragma unroll
  for (int i = 0; i < 8; ++i)
#pragma unroll
    for (int j = 0; j < 4; ++j) acc[i][j] = (f32x4){0.f, 0.f, 0.f, 0.f};

  const int aoff0 = ((l4) ^ (l15 & 7)) << 4;
  const int aoff1 = ((4 + l4) ^ (l15 & 7)) << 4;

  stageA(0, 0); stageA(0, 1);
  stageB(0, 0); stageB(0, 1);
  stageB(1, 0); stageB(1, 1);
  asm volatile("s_waitcnt vmcnt(4)" ::: "memory");
  __builtin_amdgcn_s_barrier();

  auto do_iter = [&](int t0, int last) {
    bf16x8 bfr[4][2];
#pragma unroll
    for (int p = 0; p < 8; ++p) {
      const int s = p >> 2, qd = p & 3;
      const char* aT = smem + (s * 2 + wr) * 16384 + l15 * 128;
      bf16x8 afr[2][2];
#pragma unroll
      for (int jm = 0; jm < 2; ++jm) {
        afr[jm][0] = *(const bf16x8*)(aT + (2 * qd + jm) * 2048 + aoff0);
        afr[jm][1] = *(const bf16x8*)(aT + (2 * qd + jm) * 2048 + aoff1);
      }
      if (qd == 0) {
        const char* bT = smem + 65536 + (s * 2 + (wc >> 1)) * 16384 +
                         ((wc & 1) * 64 + l15) * 128;
#pragma unroll
        for (int nf = 0; nf < 4; ++nf) {
          bfr[nf][0] = *(const bf16x8*)(bT + nf * 2048 + aoff0);
          bfr[nf][1] = *(const bf16x8*)(bT + nf * 2048 + aoff1);
        }
      }
      if (p == 0) { stageA(t0 + 1, 0); stageA(t0 + 1, 1); }
      if (!last) {
        if (p == 1) stageB(t0 + 2, 0);
        if (p == 2) stageB(t0 + 2, 1);
        if (p == 4) { stageA(t0 + 2, 0); stageA(t0 + 2, 1); }
        if (p == 5) stageB(t0 + 3, 0);
        if (p == 6) stageB(t0 + 3, 1);
      }
      if (p == 3) {
        if (last) asm volatile("s_waitcnt vmcnt(0)" ::: "memory");
        else      asm volatile("s_waitcnt vmcnt(4)" ::: "memory");
      }
      if (p == 7 && !last) asm volatile("s_waitcnt vmcnt(4)" ::: "memory");
      __builtin_amdgcn_s_barrier();
      asm volatile("s_waitcnt lgkmcnt(0)" ::: "memory");
      __builtin_amdgcn_sched_barrier(0);
      __builtin_amdgcn_s_setprio(1);
#pragma unroll
      for (int ks = 0; ks < 2; ++ks)
#pragma unroll
        for (int jm = 0; jm < 2; ++jm)
#pragma unroll
          for (int nf = 0; nf < 4; ++nf)
            acc[2 * qd + jm][nf] =
                mfma16(afr[jm][ks], bfr[nf][ks], acc[2 * qd + jm][nf]);
      __builtin_amdgcn_s_setprio(0);
      __builtin_amdgcn_s_barrier();
    }
  };

  for (int j = 0; j < 31; ++j) do_iter(2 * j, 0);
  do_iter(62, 1);

  if (MODE == 0) {
    if (n0 < 5120) {
      u16* qkp = (u16*)C0;
#pragma unroll
      for (int mf = 0; mf < 8; ++mf)
#pragma unroll
        for (int nf = 0; nf < 4; ++nf) {
          int ng = n0 + wc * 64 + nf * 16 + l15;
#pragma unroll
          for (int r = 0; r < 4; ++r) {
            int mg = m0 + wr * 128 + mf * 16 + l4 * 4 + r;
            qkp[(size_t)mg * 5120 + ng] = f2bf(acc[mf][nf][r]);
          }
        }
    } else {
#pragma unroll
      for (int mf = 0; mf < 8; ++mf)
#pragma unroll
        for (int nf = 0; nf < 4; ++nf) {
          int vr = (n0 - 5120) + wc * 64 + nf * 16 + l15;
          int mg = m0 + wr * 128 + mf * 16 + l4 * 4;
          ushort4 pk;
          pk.x = f2bf(acc[mf][nf][0]); pk.y = f2bf(acc[mf][nf][1]);
          pk.z = f2bf(acc[mf][nf][2]); pk.w = f2bf(acc[mf][nf][3]);
          *(ushort4*)&Vt[(size_t)vr * 2048 + mg] = pk;
        }
    }
  } else {
    float* Cp = (float*)C0;
#pragma unroll
    for (int mf = 0; mf < 8; ++mf)
#pragma unroll
      for (int nf = 0; nf < 4; ++nf) {
        int ng = n0 + wc * 64 + nf * 16 + l15;
#pragma unroll
        for (int r = 0; r < 4; ++r) {
          int mg = m0 + wr * 128 + mf * 16 + l4 * 4 + r;
          Cp[(size_t)mg * 4096 + ng] = acc[mf][nf][r];
        }
      }
  }
}

// ---------------- GQA flash attention (swapped-operand, 64q/wave) ----------------
// qk: [2048][5120] bf16 (post-rope, Q pre-scaled by QSCALE incl. log2e)
// vt: [1024][2048] bf16 (V transposed: row = hk*128+d, col = t)
// oat: [2048][4096] bf16
// block: 4 waves x 64 q = 256 q rows; kv step 64; grid 256 (8 qtiles x 32 heads)
// hk = bid&7 -> XCD-pinned K/V (1MB per hk, L2-resident per XCD)
__global__ __launch_bounds__(256, 1) void attn_kernel(const u16* __restrict__ qk,
                                                      const u16* __restrict__ vt,
                                                      u16* __restrict__ oat,
                                                      const float* __restrict__ mask,
                                                      const int* __restrict__ flag) {
  __shared__ u16 k_lds[2][64 * 128];  // [kv][d], 256B rows, chunk^(row&15)
  __shared__ u16 v_lds[2][64 * 128];  // [d=128][kv=64], 128B rows, chunk^(row&7)
  __shared__ u16 p_lds[4][64 * 64];   // per-wave P [q=64][kv=64], chunk^(row&7)

  const int tid = threadIdx.x, lane = tid & 63, w = tid >> 6;
  const int l15 = lane & 15, l4 = lane >> 4;
  const int bid = blockIdx.x;
  const int hk = bid & 7;          // XCD-pinned kv head
  const int rest = bid >> 3;       // 0..31
  const int h = hk * 4 + (rest & 3);
  const int qt = rest >> 2;        // 0..7
  const int qbase = qt * 256 + w * 64;

  const bool use_mask = (*flag != 0);
  const char* kbase = (const char*)qk + 8192 + (size_t)hk * 256;
  const char* vbase = (const char*)vt + (size_t)hk * 128 * 4096;

  // Q fragments: qf[qg][ks], B-operand (col=q=l15, k=d)
  bf16x8 qf[4][4];
#pragma unroll
  for (int qg = 0; qg < 4; ++qg) {
    const char* qp = (const char*)qk +
                     (size_t)(qbase + qg * 16 + l15) * 10240 + h * 256 + l4 * 16;
#pragma unroll
    for (int ks = 0; ks < 4; ++ks) qf[qg][ks] = *(const bf16x8*)(qp + ks * 64);
  }

  f32x4 oacc[4][8];
#pragma unroll
  for (int qg = 0; qg < 4; ++qg)
#pragma unroll
    for (int fd = 0; fd < 8; ++fd) oacc[qg][fd] = (f32x4){0.f, 0.f, 0.f, 0.f};
  float m_run[4] = {-1e30f, -1e30f, -1e30f, -1e30f};
  float l_run[4] = {0.f, 0.f, 0.f, 0.f};

  // hoisted swizzle offsets
  int koff[4], voff[2], poff[4];
#pragma unroll
  for (int ks = 0; ks < 4; ++ks) koff[ks] = ((4 * ks + l4) ^ l15) << 4;
#pragma unroll
  for (int ks = 0; ks < 2; ++ks) voff[ks] = ((4 * ks + l4) ^ (l15 & 7)) << 4;
#pragma unroll
  for (int f = 0; f < 4; ++f)
    poff[f] = (((2 * f + (l4 >> 1)) ^ (l15 & 7)) << 4) + 8 * (l4 & 1);
  char* pwav = (char*)p_lds[w];

#define STAGE(buf, kv0)                                                        \
  {                                                                            \
    _Pragma("unroll") for (int rd = 0; rd < 4; ++rd) {                         \
      int c = rd * 256 + tid;                                                  \
      int row = c >> 4;                                                        \
      int src = ((c & 15) ^ (row & 15)) << 4;                                  \
      gload_lds16(kbase + (size_t)((kv0) + row) * 10240 + src,                 \
                  (char*)k_lds[buf] + (rd * 256 + w * 64) * 16);               \
      int rowv = c >> 3;                                                       \
      int srcv = ((c & 7) ^ (rowv & 7)) << 4;                                  \
      gload_lds16(vbase + (size_t)rowv * 4096 + (kv0) * 2 + srcv,              \
                  (char*)v_lds[buf] + (rd * 256 + w * 64) * 16);               \
    }                                                                          \
  }

  STAGE(0, 0);
  asm volatile("s_waitcnt vmcnt(0)" ::: "memory");
  __builtin_amdgcn_s_barrier();
  __builtin_amdgcn_sched_barrier(0);

  for (int kt = 0; kt < 32; ++kt) {
    const int cur = kt & 1;
    const int kv0 = kt * 64;
    if (kt < 31) STAGE(cur ^ 1, kv0 + 64);

    // S^T = K-tile x Q  (rows = kv, cols = q)
    f32x4 sA[4][4];
#pragma unroll
    for (int qg = 0; qg < 4; ++qg)
#pragma unroll
      for (int f = 0; f < 4; ++f) sA[qg][f] = (f32x4){0.f, 0.f, 0.f, 0.f};

    __builtin_amdgcn_s_setprio(1);
#pragma unroll
    for (int ks = 0; ks < 4; ++ks) {
      bf16x8 kfr[4];
#pragma unroll
      for (int f = 0; f < 4; ++f)
        kfr[f] = *(const bf16x8*)((const char*)k_lds[cur] +
                                  (16 * f + l15) * 256 + koff[ks]);
#pragma unroll
      for (int f = 0; f < 4; ++f)
#pragma unroll
        for (int qg = 0; qg < 4; ++qg)
          sA[qg][f] = mfma16(kfr[f], qf[qg][ks], sA[qg][f]);
    }
    __builtin_amdgcn_s_setprio(0);

    if (use_mask) {
#pragma unroll
      for (int qg = 0; qg < 4; ++qg) {
        int qglob = qbase + qg * 16 + l15;
#pragma unroll
        for (int f = 0; f < 4; ++f)
#pragma unroll
          for (int r = 0; r < 4; ++r) {
            int kvglob = kv0 + 16 * f + 4 * l4 + r;
            sA[qg][f][r] += LOG2E_F * mask[(size_t)qglob * 2048 + kvglob];
          }
      }
    }

    // online softmax; q lane-local (l15), kv in (f, l4, reg)
#pragma unroll
    for (int qg = 0; qg < 4; ++qg) {
      float mx = fmaxf(fmaxf(fmaxf(sA[qg][0][0], sA[qg][0][1]),
                             fmaxf(sA[qg][0][2], sA[qg][0][3])),
                       fmaxf(fmaxf(sA[qg][1][0], sA[qg][1][1]),
                             fmaxf(sA[qg][1][2], sA[qg][1][3])));
      float mx2 = fmaxf(fmaxf(fmaxf(sA[qg][2][0], sA[qg][2][1]),
                              fmaxf(sA[qg][2][2], sA[qg][2][3])),
                        fmaxf(fmaxf(sA[qg][3][0], sA[qg][3][1]),
                              fmaxf(sA[qg][3][2], sA[qg][3][3])));
      mx = fmaxf(mx, mx2);
      mx = fmaxf(mx, __shfl_xor(mx, 16));
      mx = fmaxf(mx, __shfl_xor(mx, 32));
      if (__any(mx > m_run[qg] + 8.0f)) {
        float mnew = fmaxf(m_run[qg], mx);
        float a = exp2a(m_run[qg] - mnew);
        l_run[qg] *= a;
        m_run[qg] = mnew;
        float a0 = __shfl(a, 4 * l4 + 0);
        float a1 = __shfl(a, 4 * l4 + 1);
        float a2 = __shfl(a, 4 * l4 + 2);
        float a3 = __shfl(a, 4 * l4 + 3);
#pragma unroll
        for (int fd = 0; fd < 8; ++fd) {
          oacc[qg][fd][0] *= a0; oacc[qg][fd][1] *= a1;
          oacc[qg][fd][2] *= a2; oacc[qg][fd][3] *= a3;
        }
      }
      float ps = 0.f;
      char* pw = pwav + (qg * 16 + l15) * 128;
#pragma unroll
      for (int f = 0; f < 4; ++f) {
        float p0 = exp2a(sA[qg][f][0] - m_run[qg]);
        float p1 = exp2a(sA[qg][f][1] - m_run[qg]);
        float p2 = exp2a(sA[qg][f][2] - m_run[qg]);
        float p3 = exp2a(sA[qg][f][3] - m_run[qg]);
        ps += (p0 + p1) + (p2 + p3);
        uint2 wv;
        wv.x = cvtpk(p0, p1);
        wv.y = cvtpk(p2, p3);
        *(uint2*)(pw + poff[f]) = wv;
      }
      ps += __shfl_xor(ps, 16);
      ps += __shfl_xor(ps, 32);
      l_run[qg] += ps;
    }

    // O += P V  (A = P [q][kv] per-wave LDS, B = Vt [d][kv])
    __builtin_amdgcn_s_setprio(1);
#pragma unroll
    for (int ks = 0; ks < 2; ++ks) {
      bf16x8 pa[4];
#pragma unroll
      for (int qg = 0; qg < 4; ++qg)
        pa[qg] = *(const bf16x8*)(pwav + (qg * 16 + l15) * 128 + voff[ks]);
#pragma unroll
      for (int fd = 0; fd < 8; ++fd) {
        bf16x8 vb = *(const bf16x8*)((const char*)v_lds[cur] +
                                     (16 * fd + l15) * 128 + voff[ks]);
#pragma unroll
        for (int qg = 0; qg < 4; ++qg)
          oacc[qg][fd] = mfma16(pa[qg], vb, oacc[qg][fd]);
      }
    }
    __builtin_amdgcn_s_setprio(0);

    if (kt < 31) {
      asm volatile("s_waitcnt vmcnt(0)" ::: "memory");
      __builtin_amdgcn_s_barrier();
      __builtin_amdgcn_sched_barrier(0);
    }
  }

  // epilogue: broadcast l to C-layout lanes, normalize, write
#pragma unroll
  for (int qg = 0; qg < 4; ++qg) {
    float inv[4];
#pragma unroll
    for (int r = 0; r < 4; ++r) inv[r] = 1.0f / __shfl(l_run[qg], 4 * l4 + r);
#pragma unroll
    for (int fd = 0; fd < 8; ++fd) {
      int dg = h * 128 + 16 * fd + l15;
#pragma unroll
      for (int r = 0; r < 4; ++r) {
        int qrow = qbase + qg * 16 + 4 * l4 + r;
        oat[(size_t)qrow * 4096 + dg] = f2bf(oacc[qg][fd][r] * inv[r]);
      }
    }
  }
#undef STAGE
}

// ---------------- launch ----------------
extern "C" void kernel_launch(void* const* d_in, const int* in_sizes, int n_in,
                              void* d_out, int out_size, void* d_ws, size_t ws_size,
                              hipStream_t stream) {
  const float* x = (const float*)d_in[0];
  const int* row_ids = (const int*)d_in[1];
  const int* col_ids = (const int*)d_in[2];
  const float* mask = (const float*)d_in[3];
  const float* Wq = (const float*)d_in[4];
  const float* Wk = (const float*)d_in[5];
  const float* Wv = (const float*)d_in[6];
  const float* Wo = (const float*)d_in[7];
  const float* qw = (const float*)d_in[8];
  const float* kw = (const float*)d_in[9];

  char* ws = (char*)d_ws;
  u16* xb      = (u16*)(ws);
  u16* wqkvt   = (u16*)(ws + 16777216);
  u16* wot     = (u16*)(ws + 67108864);
  u16* qkbuf   = (u16*)(ws + 100663296);
  u16* vtbuf   = (u16*)(ws + 121634816);
  u16* oat     = (u16*)(ws + 125829120);
  float4* trig = (float4*)(ws + 142606336);
  int* flag    = (int*)(ws + 143654912);

  hipFuncSetAttribute((const void*)gemm256<0>,
                      hipFuncAttributeMaxDynamicSharedMemorySize, 131072);
  hipFuncSetAttribute((const void*)gemm256<1>,
                      hipFuncAttributeMaxDynamicSharedMemorySize, 131072);

  hipMemsetAsync(flag, 0, 4, stream);
  maskflag<<<4096, 256, 0, stream>>>((const float4*)mask, flag);
  cvt_x<<<8192, 256, 0, stream>>>((const float4*)x, (ushort4*)xb);
  tcvt<<<64 * 64, 256, 0, stream>>>(Wq, wqkvt, 4096);
  tcvt<<<64 * 16, 256, 0, stream>>>(Wk, wqkvt + (size_t)4096 * 4096, 1024);
  tcvt<<<64 * 16, 256, 0, stream>>>(Wv, wqkvt + (size_t)5120 * 4096, 1024);
  tcvt<<<64 * 64, 256, 0, stream>>>(Wo, wot, 4096);
  trig_kernel<<<256, 256, 0, stream>>>(row_ids, col_ids, trig);
  gemm256<0><<<192, 512, 131072, stream>>>(xb, wqkvt, (void*)qkbuf, vtbuf, 24);
  rope_kernel<<<2048, 256, 0, stream>>>(qkbuf, trig, qw, kw);
  attn_kernel<<<256, 256, 0, stream>>>(qkbuf, vtbuf, oat, mask, flag);
  gemm256<1><<<128, 512, 131072, stream>>>(oat, wot, d_out, nullptr, 16);
}

// Round 6
// 385.147 us; speedup vs baseline: 1.2648x; 1.1007x over previous
//
#include <hip/hip_runtime.h>
#include <hip/hip_bf16.h>

typedef unsigned short u16;
typedef __attribute__((ext_vector_type(8))) short bf16x8;
typedef __attribute__((ext_vector_type(4))) float f32x4;

#define LOG2E_F 1.4426950408889634f
#define QSCALE (0.08838834764831845f * 7.625595228825695f * 1.4426950408889634f)

__device__ __forceinline__ u16 f2bf(float f) {
  unsigned x = __float_as_uint(f);
  unsigned r = (x + 0x7fffu + ((x >> 16) & 1u)) >> 16;  // RNE
  return (u16)r;
}
__device__ __forceinline__ float bf2f(u16 u) {
  return __uint_as_float(((unsigned)u) << 16);
}
__device__ __forceinline__ float exp2a(float x) {
  float r;
  asm("v_exp_f32 %0, %1" : "=v"(r) : "v"(x));
  return r;
}
__device__ __forceinline__ unsigned cvtpk(float lo, float hi) {
  unsigned r;
  asm("v_cvt_pk_bf16_f32 %0, %1, %2" : "=v"(r) : "v"(lo), "v"(hi));
  return r;
}

__device__ __forceinline__ void gload_lds16(const void* g, void* l) {
  __builtin_amdgcn_global_load_lds(
      (__attribute__((address_space(1))) void*)(g),
      (__attribute__((address_space(3))) void*)(l), 16, 0, 0);
}

__device__ __forceinline__ f32x4 mfma16(bf16x8 a, bf16x8 b, f32x4 c) {
  return __builtin_amdgcn_mfma_f32_16x16x32_bf16(a, b, c, 0, 0, 0);
}

// ---------------- convert x: f32 -> bf16 ----------------
__global__ __launch_bounds__(256) void cvt_x(const float4* __restrict__ x,
                                             ushort4* __restrict__ xb) {
  size_t i = (size_t)blockIdx.x * 256 + threadIdx.x;
  float4 v = x[i];
  ushort4 o;
  o.x = f2bf(v.x); o.y = f2bf(v.y); o.z = f2bf(v.z); o.w = f2bf(v.w);
  xb[i] = o;
}

// ------------- transpose+convert W [4096][N] f32 -> Wt [N][4096] bf16 -------------
__global__ __launch_bounds__(256) void tcvt(const float* __restrict__ src,
                                            u16* __restrict__ dst, int N) {
  __shared__ float t[64][65];
  int bid = blockIdx.x;
  int kt = bid & 63, nt = bid >> 6;
  int k0 = kt * 64, n0 = nt * 64;
  int tid = threadIdx.x;
#pragma unroll
  for (int it = 0; it < 16; ++it) {
    int idx = it * 256 + tid;
    int row = idx >> 6, col = idx & 63;
    t[row][col] = src[(size_t)(k0 + row) * N + n0 + col];
  }
  __syncthreads();
#pragma unroll
  for (int it = 0; it < 8; ++it) {
    int idx = it * 256 + tid;
    int nrow = idx >> 5, kc = idx & 31;
    ushort2 o;
    o.x = f2bf(t[kc * 2][nrow]);
    o.y = f2bf(t[kc * 2 + 1][nrow]);
    *(ushort2*)&dst[(size_t)(n0 + nrow) * 4096 + k0 + kc * 2] = o;
  }
}

// ---------------- mask flag: nonzero detector ----------------
__global__ __launch_bounds__(256) void maskflag(const float4* __restrict__ mask,
                                                int* __restrict__ flag) {
  size_t i = (size_t)blockIdx.x * 256 + threadIdx.x;
  float4 v = mask[i];
  if (v.x != 0.f || v.y != 0.f || v.z != 0.f || v.w != 0.f) atomicOr(flag, 1);
}

// ---------------- trig tables ----------------
__global__ __launch_bounds__(256) void trig_kernel(const int* __restrict__ row_ids,
                                                   const int* __restrict__ col_ids,
                                                   float4* __restrict__ trig) {
  int idx = blockIdx.x * 256 + threadIdx.x;
  int tok = idx >> 5, i = idx & 31;
  float inv = exp2f(-(float)i * 0.41524101186092030f);
  float ar = (float)row_ids[tok] * inv;
  float ac = (float)col_ids[tok] * inv * 1.618033988749895f;
  float4 o;
  o.x = cosf(ar); o.y = sinf(ar); o.z = cosf(ac); o.w = sinf(ac);
  trig[idx] = o;
}

// ---------------- RMSNorm + gg-RoPE (in-place on QK buffer) ----------------
__global__ __launch_bounds__(256) void rope_kernel(u16* __restrict__ qk,
                                                   const float4* __restrict__ trig,
                                                   const float* __restrict__ qw,
                                                   const float* __restrict__ kw) {
  const int tok = blockIdx.x;
  const int tid = threadIdx.x;
  const int w = tid >> 6, lane = tid & 63;
  float4 t4 = trig[tok * 32 + (lane & 31)];
  float sgn = (lane < 32) ? -1.0f : 1.0f;

  for (int it = 0; it < 10; ++it) {
    int hh = w + it * 4;
    bool isQ = (hh < 32);
    int colbase = isQ ? hh * 128 : 4096 + (hh - 32) * 128;
    const float* nw = isQ ? qw : kw;
    float scale = isQ ? QSCALE : 1.0f;
    u16* p = qk + (size_t)tok * 5120 + colbase;
    float v1 = bf2f(p[lane]);
    float v2 = bf2f(p[64 + lane]);
    float w1 = nw[lane], w2 = nw[64 + lane];
    float ss = v1 * v1 + v2 * v2;
    ss += __shfl_xor(ss, 1);  ss += __shfl_xor(ss, 2);  ss += __shfl_xor(ss, 4);
    ss += __shfl_xor(ss, 8);  ss += __shfl_xor(ss, 16); ss += __shfl_xor(ss, 32);
    float rinv = rsqrtf(ss * (1.0f / 128.0f) + 1e-6f);
    float n1 = v1 * rinv * w1;
    float n2 = v2 * rinv * w2;
    float p1 = __shfl_xor(n1, 32);
    float p2 = __shfl_xor(n2, 32);
    float r1 = n1 * t4.x + sgn * p1 * t4.y;
    float r2 = n2 * t4.z + sgn * p2 * t4.w;
    p[lane]      = f2bf(r1 * scale);
    p[64 + lane] = f2bf(r2 * scale);
  }
}

// ======== 256x256 8-phase GEMM: C[M][N] = A[M][4096] * Bt[N][4096]^T ========
template <int MODE>
__global__ __launch_bounds__(512, 2) void gemm256(const u16* __restrict__ A,
                                                  const u16* __restrict__ Bt,
                                                  void* __restrict__ C0,
                                                  u16* __restrict__ Vt, int nnt) {
  extern __shared__ char smem[];  // [0,64K): A ; [64K,128K): B
  const int tid = threadIdx.x, lane = tid & 63, w = tid >> 6;
  const int l15 = lane & 15, l4 = lane >> 4;
  const int wr = w >> 2, wc = w & 3;

  const int grid = gridDim.x;
  const int wgid = (blockIdx.x & 7) * (grid >> 3) + (blockIdx.x >> 3);
  const int mt = wgid / nnt, nt = wgid % nnt;
  const int m0 = mt * 256, n0 = nt * 256;

  const int kswz = (((tid & 7) ^ ((tid >> 3) & 7)) << 4);
  const char* arow = (const char*)A + (size_t)(m0 + (tid >> 3)) * 8192 + kswz;
  const char* brow = (const char*)Bt + (size_t)(n0 + (tid >> 3)) * 8192 + kswz;

  auto stageA = [&](int t, int h) {
#pragma unroll
    for (int rd = 0; rd < 2; ++rd)
      gload_lds16(arow + (size_t)(h * 128 + rd * 64) * 8192 + t * 128,
                  smem + ((t & 1) * 2 + h) * 16384 + rd * 8192 + w * 1024);
  };
  auto stageB = [&](int t, int h) {
#pragma unroll
    for (int rd = 0; rd < 2; ++rd)
      gload_lds16(brow + (size_t)(h * 128 + rd * 64) * 8192 + t * 128,
                  smem + 65536 + ((t & 1) * 2 + h) * 16384 + rd * 8192 + w * 1024);
  };

  f32x4 acc[8][4];
#pragma unroll
  for (int i = 0; i < 8; ++i)
#pragma unroll
    for (int j = 0; j < 4; ++j) acc[i][j] = (f32x4){0.f, 0.f, 0.f, 0.f};

  const int aoff0 = ((l4) ^ (l15 & 7)) << 4;
  const int aoff1 = ((4 + l4) ^ (l15 & 7)) << 4;

  stageA(0, 0); stageA(0, 1);
  stageB(0, 0); stageB(0, 1);
  stageB(1, 0); stageB(1, 1);
  asm volatile("s_waitcnt vmcnt(4)" ::: "memory");
  __builtin_amdgcn_s_barrier();

  auto do_iter = [&](int t0, int last) {
    bf16x8 bfr[4][2];
#pragma unroll
    for (int p = 0; p < 8; ++p) {
      const int s = p >> 2, qd = p & 3;
      const char* aT = smem + (s * 2 + wr) * 16384 + l15 * 128;
      bf16x8 afr[2][2];
#pragma unroll
      for (int jm = 0; jm < 2; ++jm) {
        afr[jm][0] = *(const bf16x8*)(aT + (2 * qd + jm) * 2048 + aoff0);
        afr[jm][1] = *(const bf16x8*)(aT + (2 * qd + jm) * 2048 + aoff1);
      }
      if (qd == 0) {
        const char* bT = smem + 65536 + (s * 2 + (wc >> 1)) * 16384 +
                         ((wc & 1) * 64 + l15) * 128;
#pragma unroll
        for (int nf = 0; nf < 4; ++nf) {
          bfr[nf][0] = *(const bf16x8*)(bT + nf * 2048 + aoff0);
          bfr[nf][1] = *(const bf16x8*)(bT + nf * 2048 + aoff1);
        }
      }
      if (p == 0) { stageA(t0 + 1, 0); stageA(t0 + 1, 1); }
      if (!last) {
        if (p == 1) stageB(t0 + 2, 0);
        if (p == 2) stageB(t0 + 2, 1);
        if (p == 4) { stageA(t0 + 2, 0); stageA(t0 + 2, 1); }
        if (p == 5) stageB(t0 + 3, 0);
        if (p == 6) stageB(t0 + 3, 1);
      }
      if (p == 3) {
        if (last) asm volatile("s_waitcnt vmcnt(0)" ::: "memory");
        else      asm volatile("s_waitcnt vmcnt(4)" ::: "memory");
      }
      if (p == 7 && !last) asm volatile("s_waitcnt vmcnt(4)" ::: "memory");
      __builtin_amdgcn_s_barrier();
      asm volatile("s_waitcnt lgkmcnt(0)" ::: "memory");
      __builtin_amdgcn_sched_barrier(0);
      __builtin_amdgcn_s_setprio(1);
#pragma unroll
      for (int ks = 0; ks < 2; ++ks)
#pragma unroll
        for (int jm = 0; jm < 2; ++jm)
#pragma unroll
          for (int nf = 0; nf < 4; ++nf)
            acc[2 * qd + jm][nf] =
                mfma16(afr[jm][ks], bfr[nf][ks], acc[2 * qd + jm][nf]);
      __builtin_amdgcn_s_setprio(0);
      __builtin_amdgcn_s_barrier();
    }
  };

  for (int j = 0; j < 31; ++j) do_iter(2 * j, 0);
  do_iter(62, 1);

  if (MODE == 0) {
    if (n0 < 5120) {
      u16* qkp = (u16*)C0;
#pragma unroll
      for (int mf = 0; mf < 8; ++mf)
#pragma unroll
        for (int nf = 0; nf < 4; ++nf) {
          int ng = n0 + wc * 64 + nf * 16 + l15;
#pragma unroll
          for (int r = 0; r < 4; ++r) {
            int mg = m0 + wr * 128 + mf * 16 + l4 * 4 + r;
            qkp[(size_t)mg * 5120 + ng] = f2bf(acc[mf][nf][r]);
          }
        }
    } else {
#pragma unroll
      for (int mf = 0; mf < 8; ++mf)
#pragma unroll
        for (int nf = 0; nf < 4; ++nf) {
          int vr = (n0 - 5120) + wc * 64 + nf * 16 + l15;
          int mg = m0 + wr * 128 + mf * 16 + l4 * 4;
          ushort4 pk;
          pk.x = f2bf(acc[mf][nf][0]); pk.y = f2bf(acc[mf][nf][1]);
          pk.z = f2bf(acc[mf][nf][2]); pk.w = f2bf(acc[mf][nf][3]);
          *(ushort4*)&Vt[(size_t)vr * 2048 + mg] = pk;
        }
    }
  } else {
    float* Cp = (float*)C0;
#pragma unroll
    for (int mf = 0; mf < 8; ++mf)
#pragma unroll
      for (int nf = 0; nf < 4; ++nf) {
        int ng = n0 + wc * 64 + nf * 16 + l15;
#pragma unroll
        for (int r = 0; r < 4; ++r) {
          int mg = m0 + wr * 128 + mf * 16 + l4 * 4 + r;
          Cp[(size_t)mg * 4096 + ng] = acc[mf][nf][r];
        }
      }
  }
}

// ---------------- GQA flash attention (8 waves x 32q, in-register P) ----------------
// qk: [2048][5120] bf16 (post-rope, Q pre-scaled by QSCALE incl. log2e)
// vt: [1024][2048] bf16 (V transposed: row = hk*128+d, col = t)
// oat: [2048][4096] bf16
// block: 8 waves x 32 q = 256 q rows, 512 thr; kv step 64; grid 256 (8 qt x 32 h)
// hk = bid&7 -> XCD-pinned K/V. LDS 64KB.
__global__ __launch_bounds__(512, 2) void attn_kernel(const u16* __restrict__ qk,
                                                      const u16* __restrict__ vt,
                                                      u16* __restrict__ oat,
                                                      const float* __restrict__ mask,
                                                      const int* __restrict__ flag) {
  __shared__ u16 k_lds[2][64 * 128];  // [kv][d], 256B rows, chunk^(row&15)
  __shared__ u16 v_lds[2][64 * 128];  // [d=128][kv=64], 128B rows, chunk^(row&7)

  const int tid = threadIdx.x, lane = tid & 63, w = tid >> 6;
  const int l15 = lane & 15, l4 = lane >> 4;
  const int bid = blockIdx.x;
  const int hk = bid & 7;          // XCD-pinned kv head
  const int rest = bid >> 3;       // 0..31
  const int h = hk * 4 + (rest & 3);
  const int qt = rest >> 2;        // 0..7
  const int qbase = qt * 256 + w * 32;

  const bool use_mask = (*flag != 0);
  const char* kbase = (const char*)qk + 8192 + (size_t)hk * 256;
  const char* vbase = (const char*)vt + (size_t)hk * 128 * 4096;

  // Q fragments: qf[qg][ks], B-operand (col=q=l15, k=d)
  bf16x8 qf[2][4];
#pragma unroll
  for (int qg = 0; qg < 2; ++qg) {
    const char* qp = (const char*)qk +
                     (size_t)(qbase + qg * 16 + l15) * 10240 + h * 256 + l4 * 16;
#pragma unroll
    for (int ks = 0; ks < 4; ++ks) qf[qg][ks] = *(const bf16x8*)(qp + ks * 64);
  }

  f32x4 oacc[2][8];
#pragma unroll
  for (int qg = 0; qg < 2; ++qg)
#pragma unroll
    for (int fd = 0; fd < 8; ++fd) oacc[qg][fd] = (f32x4){0.f, 0.f, 0.f, 0.f};
  float m_run[2] = {-1e30f, -1e30f};
  float l_run[2] = {0.f, 0.f};

  // hoisted swizzle offsets
  int koff[4], voff[2];
#pragma unroll
  for (int ks = 0; ks < 4; ++ks) koff[ks] = ((4 * ks + l4) ^ l15) << 4;
#pragma unroll
  for (int ks = 0; ks < 2; ++ks) voff[ks] = ((4 * ks + l4) ^ (l15 & 7)) << 4;

  // 512-thread staging: K 1024 chunks (16/row), V 1024 chunks (8/row)
#define STAGE(buf, kv0)                                                        \
  {                                                                            \
    _Pragma("unroll") for (int rd = 0; rd < 2; ++rd) {                         \
      int c = rd * 512 + tid;                                                  \
      int row = c >> 4;                                                        \
      int src = ((c & 15) ^ (row & 15)) << 4;                                  \
      gload_lds16(kbase + (size_t)((kv0) + row) * 10240 + src,                 \
                  (char*)k_lds[buf] + (rd * 512 + w * 64) * 16);               \
      int rowv = c >> 3;                                                       \
      int srcv = ((c & 7) ^ (rowv & 7)) << 4;                                  \
      gload_lds16(vbase + (size_t)rowv * 4096 + (kv0) * 2 + srcv,              \
                  (char*)v_lds[buf] + (rd * 512 + w * 64) * 16);               \
    }                                                                          \
  }

  STAGE(0, 0);
  asm volatile("s_waitcnt vmcnt(0)" ::: "memory");
  __builtin_amdgcn_s_barrier();
  __builtin_amdgcn_sched_barrier(0);

  for (int kt = 0; kt < 32; ++kt) {
    const int cur = kt & 1;
    const int kv0 = kt * 64;
    if (kt < 31) STAGE(cur ^ 1, kv0 + 64);

    // S^T = K-tile x Q  (rows = kv, cols = q = l15)
    f32x4 sA[2][4];
#pragma unroll
    for (int qg = 0; qg < 2; ++qg)
#pragma unroll
      for (int f = 0; f < 4; ++f) sA[qg][f] = (f32x4){0.f, 0.f, 0.f, 0.f};

    __builtin_amdgcn_s_setprio(1);
#pragma unroll
    for (int ks = 0; ks < 4; ++ks) {
      bf16x8 kfr[4];
#pragma unroll
      for (int f = 0; f < 4; ++f)
        kfr[f] = *(const bf16x8*)((const char*)k_lds[cur] +
                                  (16 * f + l15) * 256 + koff[ks]);
#pragma unroll
      for (int f = 0; f < 4; ++f) {
        sA[0][f] = mfma16(kfr[f], qf[0][ks], sA[0][f]);
        sA[1][f] = mfma16(kfr[f], qf[1][ks], sA[1][f]);
      }
    }
    __builtin_amdgcn_s_setprio(0);

    if (use_mask) {
#pragma unroll
      for (int qg = 0; qg < 2; ++qg) {
        int qglob = qbase + qg * 16 + l15;
#pragma unroll
        for (int f = 0; f < 4; ++f)
#pragma unroll
          for (int r = 0; r < 4; ++r) {
            int kvglob = kv0 + 16 * f + 4 * l4 + r;
            sA[qg][f][r] += LOG2E_F * mask[(size_t)qglob * 2048 + kvglob];
          }
      }
    }

    // online softmax; q lane-local (l15), kv in (f, l4, reg).
    // P packed to bf16 then redistributed in-register to PV A-fragment layout.
    // Target word (ks,wd) at lane (l15,l4) holds kv pair 32ks+8l4+2wd from
    //   source lane l15 + 16*(2*(l4&1)+(wd>>1)), selecting W[2ks+(l4>>1)][wd&1].
    // Selection must happen on the DESTINATION (source can't know the consumer),
    //   so broadcast both f-blocks and cndmask on (l4&2).
    unsigned paw[2][2][4];
#pragma unroll
    for (int qg = 0; qg < 2; ++qg) {
      float mx = fmaxf(fmaxf(fmaxf(sA[qg][0][0], sA[qg][0][1]),
                             fmaxf(sA[qg][0][2], sA[qg][0][3])),
                       fmaxf(fmaxf(sA[qg][1][0], sA[qg][1][1]),
                             fmaxf(sA[qg][1][2], sA[qg][1][3])));
      float mx2 = fmaxf(fmaxf(fmaxf(sA[qg][2][0], sA[qg][2][1]),
                              fmaxf(sA[qg][2][2], sA[qg][2][3])),
                        fmaxf(fmaxf(sA[qg][3][0], sA[qg][3][1]),
                              fmaxf(sA[qg][3][2], sA[qg][3][3])));
      mx = fmaxf(mx, mx2);
      mx = fmaxf(mx, __shfl_xor(mx, 16));
      mx = fmaxf(mx, __shfl_xor(mx, 32));
      if (__any(mx > m_run[qg] + 8.0f)) {
        float mnew = fmaxf(m_run[qg], mx);
        float a = exp2a(m_run[qg] - mnew);
        l_run[qg] *= a;
        m_run[qg] = mnew;
        float a0 = __shfl(a, 4 * l4 + 0);
        float a1 = __shfl(a, 4 * l4 + 1);
        float a2 = __shfl(a, 4 * l4 + 2);
        float a3 = __shfl(a, 4 * l4 + 3);
#pragma unroll
        for (int fd = 0; fd < 8; ++fd) {
          oacc[qg][fd][0] *= a0; oacc[qg][fd][1] *= a1;
          oacc[qg][fd][2] *= a2; oacc[qg][fd][3] *= a3;
        }
      }
      float ps = 0.f;
      unsigned W[4][2];
#pragma unroll
      for (int f = 0; f < 4; ++f) {
        float p0 = exp2a(sA[qg][f][0] - m_run[qg]);
        float p1 = exp2a(sA[qg][f][1] - m_run[qg]);
        float p2 = exp2a(sA[qg][f][2] - m_run[qg]);
        float p3 = exp2a(sA[qg][f][3] - m_run[qg]);
        ps += (p0 + p1) + (p2 + p3);
        W[f][0] = cvtpk(p0, p1);
        W[f][1] = cvtpk(p2, p3);
      }
      ps += __shfl_xor(ps, 16);
      ps += __shfl_xor(ps, 32);
      l_run[qg] += ps;
#pragma unroll
      for (int ks = 0; ks < 2; ++ks)
#pragma unroll
        for (int wd = 0; wd < 4; ++wd) {
          int src = l15 + 16 * (2 * (l4 & 1) + (wd >> 1));
          unsigned v0 = (unsigned)__shfl((int)W[2 * ks][wd & 1], src);
          unsigned v1 = (unsigned)__shfl((int)W[2 * ks + 1][wd & 1], src);
          paw[qg][ks][wd] = (l4 & 2) ? v1 : v0;
        }
    }

    // O += P V  (A = P in registers, B = Vt [d][kv] from LDS)
    __builtin_amdgcn_s_setprio(1);
#pragma unroll
    for (int ks = 0; ks < 2; ++ks) {
      union { unsigned u[4]; bf16x8 v; } pa0, pa1;
#pragma unroll
      for (int wd = 0; wd < 4; ++wd) {
        pa0.u[wd] = paw[0][ks][wd];
        pa1.u[wd] = paw[1][ks][wd];
      }
#pragma unroll
      for (int fd = 0; fd < 8; ++fd) {
        bf16x8 vb = *(const bf16x8*)((const char*)v_lds[cur] +
                                     (16 * fd + l15) * 128 + voff[ks]);
        oacc[0][fd] = mfma16(pa0.v, vb, oacc[0][fd]);
        oacc[1][fd] = mfma16(pa1.v, vb, oacc[1][fd]);
      }
    }
    __builtin_amdgcn_s_setprio(0);

    if (kt < 31) {
      asm volatile("s_waitcnt vmcnt(0)" ::: "memory");
      __builtin_amdgcn_s_barrier();
      __builtin_amdgcn_sched_barrier(0);
    }
  }

  // epilogue: broadcast l to C-layout lanes, normalize, write
#pragma unroll
  for (int qg = 0; qg < 2; ++qg) {
    float inv[4];
#pragma unroll
    for (int r = 0; r < 4; ++r) inv[r] = 1.0f / __shfl(l_run[qg], 4 * l4 + r);
#pragma unroll
    for (int fd = 0; fd < 8; ++fd) {
      int dg = h * 128 + 16 * fd + l15;
#pragma unroll
      for (int r = 0; r < 4; ++r) {
        int qrow = qbase + qg * 16 + 4 * l4 + r;
        oat[(size_t)qrow * 4096 + dg] = f2bf(oacc[qg][fd][r] * inv[r]);
      }
    }
  }
#undef STAGE
}

// ---------------- launch ----------------
extern "C" void kernel_launch(void* const* d_in, const int* in_sizes, int n_in,
                              void* d_out, int out_size, void* d_ws, size_t ws_size,
                              hipStream_t stream) {
  const float* x = (const float*)d_in[0];
  const int* row_ids = (const int*)d_in[1];
  const int* col_ids = (const int*)d_in[2];
  const float* mask = (const float*)d_in[3];
  const float* Wq = (const float*)d_in[4];
  const float* Wk = (const float*)d_in[5];
  const float* Wv = (const float*)d_in[6];
  const float* Wo = (const float*)d_in[7];
  const float* qw = (const float*)d_in[8];
  const float* kw = (const float*)d_in[9];

  char* ws = (char*)d_ws;
  u16* xb      = (u16*)(ws);
  u16* wqkvt   = (u16*)(ws + 16777216);
  u16* wot     = (u16*)(ws + 67108864);
  u16* qkbuf   = (u16*)(ws + 100663296);
  u16* vtbuf   = (u16*)(ws + 121634816);
  u16* oat     = (u16*)(ws + 125829120);
  float4* trig = (float4*)(ws + 142606336);
  int* flag    = (int*)(ws + 143654912);

  hipFuncSetAttribute((const void*)gemm256<0>,
                      hipFuncAttributeMaxDynamicSharedMemorySize, 131072);
  hipFuncSetAttribute((const void*)gemm256<1>,
                      hipFuncAttributeMaxDynamicSharedMemorySize, 131072);

  hipMemsetAsync(flag, 0, 4, stream);
  maskflag<<<4096, 256, 0, stream>>>((const float4*)mask, flag);
  cvt_x<<<8192, 256, 0, stream>>>((const float4*)x, (ushort4*)xb);
  tcvt<<<64 * 64, 256, 0, stream>>>(Wq, wqkvt, 4096);
  tcvt<<<64 * 16, 256, 0, stream>>>(Wk, wqkvt + (size_t)4096 * 4096, 1024);
  tcvt<<<64 * 16, 256, 0, stream>>>(Wv, wqkvt + (size_t)5120 * 4096, 1024);
  tcvt<<<64 * 64, 256, 0, stream>>>(Wo, wot, 4096);
  trig_kernel<<<256, 256, 0, stream>>>(row_ids, col_ids, trig);
  gemm256<0><<<192, 512, 131072, stream>>>(xb, wqkvt, (void*)qkbuf, vtbuf, 24);
  rope_kernel<<<2048, 256, 0, stream>>>(qkbuf, trig, qw, kw);
  attn_kernel<<<256, 512, 0, stream>>>(qkbuf, vtbuf, oat, mask, flag);
  gemm256<1><<<128, 512, 131072, stream>>>(oat, wot, d_out, nullptr, 16);
}

// Round 7
// 365.133 us; speedup vs baseline: 1.3341x; 1.0548x over previous
//
#include <hip/hip_runtime.h>
#include <hip/hip_bf16.h>

typedef unsigned short u16;
typedef __attribute__((ext_vector_type(8))) short bf16x8;
typedef __attribute__((ext_vector_type(4))) float f32x4;

#define LOG2E_F 1.4426950408889634f
#define QSCALE (0.08838834764831845f * 7.625595228825695f * 1.4426950408889634f)

__device__ __forceinline__ u16 f2bf(float f) {
  unsigned x = __float_as_uint(f);
  unsigned r = (x + 0x7fffu + ((x >> 16) & 1u)) >> 16;  // RNE
  return (u16)r;
}
__device__ __forceinline__ float bf2f(u16 u) {
  return __uint_as_float(((unsigned)u) << 16);
}
__device__ __forceinline__ float exp2a(float x) {
  float r;
  asm("v_exp_f32 %0, %1" : "=v"(r) : "v"(x));
  return r;
}
__device__ __forceinline__ unsigned cvtpk(float lo, float hi) {
  unsigned r;
  asm("v_cvt_pk_bf16_f32 %0, %1, %2" : "=v"(r) : "v"(lo), "v"(hi));
  return r;
}

__device__ __forceinline__ void gload_lds16(const void* g, void* l) {
  __builtin_amdgcn_global_load_lds(
      (__attribute__((address_space(1))) void*)(g),
      (__attribute__((address_space(3))) void*)(l), 16, 0, 0);
}

__device__ __forceinline__ f32x4 mfma16(bf16x8 a, bf16x8 b, f32x4 c) {
  return __builtin_amdgcn_mfma_f32_16x16x32_bf16(a, b, c, 0, 0, 0);
}

// ---------------- convert x: f32 -> bf16 ----------------
__global__ __launch_bounds__(256) void cvt_x(const float4* __restrict__ x,
                                             ushort4* __restrict__ xb) {
  size_t i = (size_t)blockIdx.x * 256 + threadIdx.x;
  float4 v = x[i];
  ushort4 o;
  o.x = f2bf(v.x); o.y = f2bf(v.y); o.z = f2bf(v.z); o.w = f2bf(v.w);
  xb[i] = o;
}

// ------------- transpose+convert W [4096][N] f32 -> Wt [N][4096] bf16 -------------
__global__ __launch_bounds__(256) void tcvt(const float* __restrict__ src,
                                            u16* __restrict__ dst, int N) {
  __shared__ float t[64][65];
  int bid = blockIdx.x;
  int kt = bid & 63, nt = bid >> 6;
  int k0 = kt * 64, n0 = nt * 64;
  int tid = threadIdx.x;
#pragma unroll
  for (int it = 0; it < 16; ++it) {
    int idx = it * 256 + tid;
    int row = idx >> 6, col = idx & 63;
    t[row][col] = src[(size_t)(k0 + row) * N + n0 + col];
  }
  __syncthreads();
#pragma unroll
  for (int it = 0; it < 8; ++it) {
    int idx = it * 256 + tid;
    int nrow = idx >> 5, kc = idx & 31;
    ushort2 o;
    o.x = f2bf(t[kc * 2][nrow]);
    o.y = f2bf(t[kc * 2 + 1][nrow]);
    *(ushort2*)&dst[(size_t)(n0 + nrow) * 4096 + k0 + kc * 2] = o;
  }
}

// ---------------- mask flag: nonzero detector ----------------
__global__ __launch_bounds__(256) void maskflag(const float4* __restrict__ mask,
                                                int* __restrict__ flag) {
  size_t i = (size_t)blockIdx.x * 256 + threadIdx.x;
  float4 v = mask[i];
  if (v.x != 0.f || v.y != 0.f || v.z != 0.f || v.w != 0.f) atomicOr(flag, 1);
}

// ---------------- trig tables ----------------
__global__ __launch_bounds__(256) void trig_kernel(const int* __restrict__ row_ids,
                                                   const int* __restrict__ col_ids,
                                                   float4* __restrict__ trig) {
  int idx = blockIdx.x * 256 + threadIdx.x;
  int tok = idx >> 5, i = idx & 31;
  float inv = exp2f(-(float)i * 0.41524101186092030f);
  float ar = (float)row_ids[tok] * inv;
  float ac = (float)col_ids[tok] * inv * 1.618033988749895f;
  float4 o;
  o.x = cosf(ar); o.y = sinf(ar); o.z = cosf(ac); o.w = sinf(ac);
  trig[idx] = o;
}

// ---------------- RMSNorm + gg-RoPE (in-place on QK buffer) ----------------
__global__ __launch_bounds__(256) void rope_kernel(u16* __restrict__ qk,
                                                   const float4* __restrict__ trig,
                                                   const float* __restrict__ qw,
                                                   const float* __restrict__ kw) {
  const int tok = blockIdx.x;
  const int tid = threadIdx.x;
  const int w = tid >> 6, lane = tid & 63;
  float4 t4 = trig[tok * 32 + (lane & 31)];
  float sgn = (lane < 32) ? -1.0f : 1.0f;

  for (int it = 0; it < 10; ++it) {
    int hh = w + it * 4;
    bool isQ = (hh < 32);
    int colbase = isQ ? hh * 128 : 4096 + (hh - 32) * 128;
    const float* nw = isQ ? qw : kw;
    float scale = isQ ? QSCALE : 1.0f;
    u16* p = qk + (size_t)tok * 5120 + colbase;
    float v1 = bf2f(p[lane]);
    float v2 = bf2f(p[64 + lane]);
    float w1 = nw[lane], w2 = nw[64 + lane];
    float ss = v1 * v1 + v2 * v2;
    ss += __shfl_xor(ss, 1);  ss += __shfl_xor(ss, 2);  ss += __shfl_xor(ss, 4);
    ss += __shfl_xor(ss, 8);  ss += __shfl_xor(ss, 16); ss += __shfl_xor(ss, 32);
    float rinv = rsqrtf(ss * (1.0f / 128.0f) + 1e-6f);
    float n1 = v1 * rinv * w1;
    float n2 = v2 * rinv * w2;
    float p1 = __shfl_xor(n1, 32);
    float p2 = __shfl_xor(n2, 32);
    float r1 = n1 * t4.x + sgn * p1 * t4.y;
    float r2 = n2 * t4.z + sgn * p2 * t4.w;
    p[lane]      = f2bf(r1 * scale);
    p[64 + lane] = f2bf(r2 * scale);
  }
}

// ======== 256-wide 8-phase GEMM: C[M][N] = A[M][4096] * Bt[N][4096]^T ========
// MODE 0: BM=256, BN=192 -> grid 8x32=256 (1/CU). Out: qk bf16 / Vt transposed.
// MODE 1: BM=256, BN=256, split-K=2 -> grid 2x128=256 (1/CU). Out: f32 partials.
// LDS: A [2 slots][2 halves][128 rows][64k] = 64KB @0; B @64KB:
//   MODE0: [2 slots][192 rows][64k] = 48KB ; MODE1: [2][2][128][64] = 64KB.
template <int MODE>
__global__ __launch_bounds__(512, 2) void gemm256(const u16* __restrict__ A,
                                                  const u16* __restrict__ Bt,
                                                  void* __restrict__ C0,
                                                  u16* __restrict__ Vt, int nnt) {
  extern __shared__ char smem[];
  const int tid = threadIdx.x, lane = tid & 63, w = tid >> 6;
  const int l15 = lane & 15, l4 = lane >> 4;
  const int wr = w >> 2, wc = w & 3;
  constexpr int NF = (MODE == 0) ? 3 : 4;
  constexpr int BNW = (MODE == 0) ? 48 : 64;  // per-wave N cols

  int wgid = (blockIdx.x & 7) * (gridDim.x >> 3) + (blockIdx.x >> 3);
  int kh = 0;
  if (MODE == 1) { kh = wgid >> 7; wgid &= 127; }
  const int mt = wgid / nnt, nt = wgid % nnt;
  const int m0 = mt * 256;
  const int n0 = nt * ((MODE == 0) ? 192 : 256);
  const int tbase = kh * 32;

  const int kswz = (((tid & 7) ^ ((tid >> 3) & 7)) << 4);
  const char* arow = (const char*)A + (size_t)(m0 + (tid >> 3)) * 8192 + kswz;
  const char* brow = (const char*)Bt + (size_t)(n0 + (tid >> 3)) * 8192 + kswz;

  auto stageA = [&](int t, int h) {
#pragma unroll
    for (int rd = 0; rd < 2; ++rd)
      gload_lds16(arow + (size_t)(h * 128 + rd * 64) * 8192 + t * 128,
                  smem + ((t & 1) * 2 + h) * 16384 + rd * 8192 + w * 1024);
  };
  auto stageB0 = [&](int t) {  // MODE0: 192 rows, 3 rounds
#pragma unroll
    for (int rd = 0; rd < 3; ++rd)
      gload_lds16(brow + (size_t)(rd * 64) * 8192 + t * 128,
                  smem + 65536 + (t & 1) * 24576 + rd * 8192 + w * 1024);
  };
  auto stageB1 = [&](int t, int h) {  // MODE1: 256 rows, 2 halves
#pragma unroll
    for (int rd = 0; rd < 2; ++rd)
      gload_lds16(brow + (size_t)(h * 128 + rd * 64) * 8192 + t * 128,
                  smem + 65536 + ((t & 1) * 2 + h) * 16384 + rd * 8192 + w * 1024);
  };

  f32x4 acc[8][NF];
#pragma unroll
  for (int i = 0; i < 8; ++i)
#pragma unroll
    for (int j = 0; j < NF; ++j) acc[i][j] = (f32x4){0.f, 0.f, 0.f, 0.f};

  const int aoff0 = ((l4) ^ (l15 & 7)) << 4;
  const int aoff1 = ((4 + l4) ^ (l15 & 7)) << 4;

  // prologue
  stageA(tbase, 0); stageA(tbase, 1);
  if constexpr (MODE == 0) {
    stageB0(tbase); stageB0(tbase + 1);
    asm volatile("s_waitcnt vmcnt(3)" ::: "memory");
  } else {
    stageB1(tbase, 0); stageB1(tbase, 1);
    stageB1(tbase + 1, 0); stageB1(tbase + 1, 1);
    asm volatile("s_waitcnt vmcnt(4)" ::: "memory");
  }
  __builtin_amdgcn_s_barrier();

  auto do_iter = [&](int t0, int last) {
    bf16x8 bfr[NF][2];
#pragma unroll
    for (int p = 0; p < 8; ++p) {
      const int s = p >> 2, qd = p & 3;
      const char* aT = smem + (s * 2 + wr) * 16384 + l15 * 128;
      bf16x8 afr[2][2];
#pragma unroll
      for (int jm = 0; jm < 2; ++jm) {
        afr[jm][0] = *(const bf16x8*)(aT + (2 * qd + jm) * 2048 + aoff0);
        afr[jm][1] = *(const bf16x8*)(aT + (2 * qd + jm) * 2048 + aoff1);
      }
      if (qd == 0) {
        const char* bT;
        if constexpr (MODE == 0)
          bT = smem + 65536 + s * 24576 + (wc * 48 + l15) * 128;
        else
          bT = smem + 65536 + (s * 2 + (wc >> 1)) * 16384 +
               ((wc & 1) * 64 + l15) * 128;
#pragma unroll
        for (int nf = 0; nf < NF; ++nf) {
          bfr[nf][0] = *(const bf16x8*)(bT + nf * 2048 + aoff0);
          bfr[nf][1] = *(const bf16x8*)(bT + nf * 2048 + aoff1);
        }
      }
      if (p == 0) { stageA(t0 + 1, 0); stageA(t0 + 1, 1); }
      if (!last) {
        if constexpr (MODE == 0) {
          if (p == 1) stageB0(t0 + 2);
          if (p == 5) stageB0(t0 + 3);
        } else {
          if (p == 1) stageB1(t0 + 2, 0);
          if (p == 2) stageB1(t0 + 2, 1);
          if (p == 5) stageB1(t0 + 3, 0);
          if (p == 6) stageB1(t0 + 3, 1);
        }
        if (p == 4) { stageA(t0 + 2, 0); stageA(t0 + 2, 1); }
      }
      if (p == 3) {
        if (last) asm volatile("s_waitcnt vmcnt(0)" ::: "memory");
        else if constexpr (MODE == 0)
          asm volatile("s_waitcnt vmcnt(3)" ::: "memory");
        else
          asm volatile("s_waitcnt vmcnt(4)" ::: "memory");
      }
      if (p == 7 && !last) {
        if constexpr (MODE == 0)
          asm volatile("s_waitcnt vmcnt(3)" ::: "memory");
        else
          asm volatile("s_waitcnt vmcnt(4)" ::: "memory");
      }
      __builtin_amdgcn_s_barrier();
      asm volatile("s_waitcnt lgkmcnt(0)" ::: "memory");
      __builtin_amdgcn_sched_barrier(0);
      __builtin_amdgcn_s_setprio(1);
#pragma unroll
      for (int ks = 0; ks < 2; ++ks)
#pragma unroll
        for (int jm = 0; jm < 2; ++jm)
#pragma unroll
          for (int nf = 0; nf < NF; ++nf)
            acc[2 * qd + jm][nf] =
                mfma16(afr[jm][ks], bfr[nf][ks], acc[2 * qd + jm][nf]);
      __builtin_amdgcn_s_setprio(0);
      __builtin_amdgcn_s_barrier();
    }
  };

  constexpr int NIT = (MODE == 0) ? 32 : 16;
  for (int j = 0; j < NIT - 1; ++j) do_iter(tbase + 2 * j, 0);
  do_iter(tbase + 2 * (NIT - 1), 1);

  // ---- epilogue ----
  if (MODE == 0) {
    u16* qkp = (u16*)C0;
#pragma unroll
    for (int mf = 0; mf < 8; ++mf)
#pragma unroll
      for (int nf = 0; nf < NF; ++nf) {
        int ng = n0 + wc * BNW + nf * 16 + l15;
        if (ng < 5120) {
#pragma unroll
          for (int r = 0; r < 4; ++r) {
            int mg = m0 + wr * 128 + mf * 16 + l4 * 4 + r;
            qkp[(size_t)mg * 5120 + ng] = f2bf(acc[mf][nf][r]);
          }
        } else {
          int vr = ng - 5120;
          int mg = m0 + wr * 128 + mf * 16 + l4 * 4;
          ushort4 pk;
          pk.x = f2bf(acc[mf][nf][0]); pk.y = f2bf(acc[mf][nf][1]);
          pk.z = f2bf(acc[mf][nf][2]); pk.w = f2bf(acc[mf][nf][3]);
          *(ushort4*)&Vt[(size_t)vr * 2048 + mg] = pk;
        }
      }
  } else {
    float* Cp = (float*)C0 + (size_t)kh * 8388608;
#pragma unroll
    for (int mf = 0; mf < 8; ++mf)
#pragma unroll
      for (int nf = 0; nf < NF; ++nf) {
        int ng = n0 + wc * BNW + nf * 16 + l15;
#pragma unroll
        for (int r = 0; r < 4; ++r) {
          int mg = m0 + wr * 128 + mf * 16 + l4 * 4 + r;
          Cp[(size_t)mg * 4096 + ng] = acc[mf][nf][r];
        }
      }
  }
}

// ---------------- split-K reduce: out = p0 + p1 ----------------
__global__ __launch_bounds__(256) void reduce2(const float4* __restrict__ p0,
                                               const float4* __restrict__ p1,
                                               float4* __restrict__ out) {
  size_t i = (size_t)blockIdx.x * 256 + threadIdx.x;
  float4 a = p0[i], b = p1[i];
  float4 o;
  o.x = a.x + b.x; o.y = a.y + b.y; o.z = a.z + b.z; o.w = a.w + b.w;
  out[i] = o;
}

// ---------------- GQA flash attention (8 waves x 32q, in-register P) ----------------
__global__ __launch_bounds__(512, 2) void attn_kernel(const u16* __restrict__ qk,
                                                      const u16* __restrict__ vt,
                                                      u16* __restrict__ oat,
                                                      const float* __restrict__ mask,
                                                      const int* __restrict__ flag) {
  __shared__ u16 k_lds[2][64 * 128];  // [kv][d], 256B rows, chunk^(row&15)
  __shared__ u16 v_lds[2][64 * 128];  // [d=128][kv=64], 128B rows, chunk^(row&7)

  const int tid = threadIdx.x, lane = tid & 63, w = tid >> 6;
  const int l15 = lane & 15, l4 = lane >> 4;
  const int bid = blockIdx.x;
  const int hk = bid & 7;          // XCD-pinned kv head
  const int rest = bid >> 3;       // 0..31
  const int h = hk * 4 + (rest & 3);
  const int qt = rest >> 2;        // 0..7
  const int qbase = qt * 256 + w * 32;

  const bool use_mask = (*flag != 0);
  const char* kbase = (const char*)qk + 8192 + (size_t)hk * 256;
  const char* vbase = (const char*)vt + (size_t)hk * 128 * 4096;

  bf16x8 qf[2][4];
#pragma unroll
  for (int qg = 0; qg < 2; ++qg) {
    const char* qp = (const char*)qk +
                     (size_t)(qbase + qg * 16 + l15) * 10240 + h * 256 + l4 * 16;
#pragma unroll
    for (int ks = 0; ks < 4; ++ks) qf[qg][ks] = *(const bf16x8*)(qp + ks * 64);
  }

  f32x4 oacc[2][8];
#pragma unroll
  for (int qg = 0; qg < 2; ++qg)
#pragma unroll
    for (int fd = 0; fd < 8; ++fd) oacc[qg][fd] = (f32x4){0.f, 0.f, 0.f, 0.f};
  float m_run[2] = {-1e30f, -1e30f};
  float l_run[2] = {0.f, 0.f};

  int koff[4], voff[2];
#pragma unroll
  for (int ks = 0; ks < 4; ++ks) koff[ks] = ((4 * ks + l4) ^ l15) << 4;
#pragma unroll
  for (int ks = 0; ks < 2; ++ks) voff[ks] = ((4 * ks + l4) ^ (l15 & 7)) << 4;

#define STAGE(buf, kv0)                                                        \
  {                                                                            \
    _Pragma("unroll") for (int rd = 0; rd < 2; ++rd) {                         \
      int c = rd * 512 + tid;                                                  \
      int row = c >> 4;                                                        \
      int src = ((c & 15) ^ (row & 15)) << 4;                                  \
      gload_lds16(kbase + (size_t)((kv0) + row) * 10240 + src,                 \
                  (char*)k_lds[buf] + (rd * 512 + w * 64) * 16);               \
      int rowv = c >> 3;                                                       \
      int srcv = ((c & 7) ^ (rowv & 7)) << 4;                                  \
      gload_lds16(vbase + (size_t)rowv * 4096 + (kv0) * 2 + srcv,              \
                  (char*)v_lds[buf] + (rd * 512 + w * 64) * 16);               \
    }                                                                          \
  }

  STAGE(0, 0);
  asm volatile("s_waitcnt vmcnt(0)" ::: "memory");
  __builtin_amdgcn_s_barrier();
  __builtin_amdgcn_sched_barrier(0);

  for (int kt = 0; kt < 32; ++kt) {
    const int cur = kt & 1;
    const int kv0 = kt * 64;
    if (kt < 31) STAGE(cur ^ 1, kv0 + 64);

    f32x4 sA[2][4];
#pragma unroll
    for (int qg = 0; qg < 2; ++qg)
#pragma unroll
      for (int f = 0; f < 4; ++f) sA[qg][f] = (f32x4){0.f, 0.f, 0.f, 0.f};

    __builtin_amdgcn_s_setprio(1);
#pragma unroll
    for (int ks = 0; ks < 4; ++ks) {
      bf16x8 kfr[4];
#pragma unroll
      for (int f = 0; f < 4; ++f)
        kfr[f] = *(const bf16x8*)((const char*)k_lds[cur] +
                                  (16 * f + l15) * 256 + koff[ks]);
#pragma unroll
      for (int f = 0; f < 4; ++f) {
        sA[0][f] = mfma16(kfr[f], qf[0][ks], sA[0][f]);
        sA[1][f] = mfma16(kfr[f], qf[1][ks], sA[1][f]);
      }
    }
    __builtin_amdgcn_s_setprio(0);

    if (use_mask) {
#pragma unroll
      for (int qg = 0; qg < 2; ++qg) {
        int qglob = qbase + qg * 16 + l15;
#pragma unroll
        for (int f = 0; f < 4; ++f)
#pragma unroll
          for (int r = 0; r < 4; ++r) {
            int kvglob = kv0 + 16 * f + 4 * l4 + r;
            sA[qg][f][r] += LOG2E_F * mask[(size_t)qglob * 2048 + kvglob];
          }
      }
    }

    unsigned paw[2][2][4];
#pragma unroll
    for (int qg = 0; qg < 2; ++qg) {
      float mx = fmaxf(fmaxf(fmaxf(sA[qg][0][0], sA[qg][0][1]),
                             fmaxf(sA[qg][0][2], sA[qg][0][3])),
                       fmaxf(fmaxf(sA[qg][1][0], sA[qg][1][1]),
                             fmaxf(sA[qg][1][2], sA[qg][1][3])));
      float mx2 = fmaxf(fmaxf(fmaxf(sA[qg][2][0], sA[qg][2][1]),
                              fmaxf(sA[qg][2][2], sA[qg][2][3])),
                        fmaxf(fmaxf(sA[qg][3][0], sA[qg][3][1]),
                              fmaxf(sA[qg][3][2], sA[qg][3][3])));
      mx = fmaxf(mx, mx2);
      mx = fmaxf(mx, __shfl_xor(mx, 16));
      mx = fmaxf(mx, __shfl_xor(mx, 32));
      if (__any(mx > m_run[qg] + 8.0f)) {
        float mnew = fmaxf(m_run[qg], mx);
        float a = exp2a(m_run[qg] - mnew);
        l_run[qg] *= a;
        m_run[qg] = mnew;
        float a0 = __shfl(a, 4 * l4 + 0);
        float a1 = __shfl(a, 4 * l4 + 1);
        float a2 = __shfl(a, 4 * l4 + 2);
        float a3 = __shfl(a, 4 * l4 + 3);
#pragma unroll
        for (int fd = 0; fd < 8; ++fd) {
          oacc[qg][fd][0] *= a0; oacc[qg][fd][1] *= a1;
          oacc[qg][fd][2] *= a2; oacc[qg][fd][3] *= a3;
        }
      }
      float ps = 0.f;
      unsigned W[4][2];
#pragma unroll
      for (int f = 0; f < 4; ++f) {
        float p0 = exp2a(sA[qg][f][0] - m_run[qg]);
        float p1 = exp2a(sA[qg][f][1] - m_run[qg]);
        float p2 = exp2a(sA[qg][f][2] - m_run[qg]);
        float p3 = exp2a(sA[qg][f][3] - m_run[qg]);
        ps += (p0 + p1) + (p2 + p3);
        W[f][0] = cvtpk(p0, p1);
        W[f][1] = cvtpk(p2, p3);
      }
      ps += __shfl_xor(ps, 16);
      ps += __shfl_xor(ps, 32);
      l_run[qg] += ps;
#pragma unroll
      for (int ks = 0; ks < 2; ++ks)
#pragma unroll
        for (int wd = 0; wd < 4; ++wd) {
          int src = l15 + 16 * (2 * (l4 & 1) + (wd >> 1));
          unsigned v0 = (unsigned)__shfl((int)W[2 * ks][wd & 1], src);
          unsigned v1 = (unsigned)__shfl((int)W[2 * ks + 1][wd & 1], src);
          paw[qg][ks][wd] = (l4 & 2) ? v1 : v0;
        }
    }

    __builtin_amdgcn_s_setprio(1);
#pragma unroll
    for (int ks = 0; ks < 2; ++ks) {
      union { unsigned u[4]; bf16x8 v; } pa0, pa1;
#pragma unroll
      for (int wd = 0; wd < 4; ++wd) {
        pa0.u[wd] = paw[0][ks][wd];
        pa1.u[wd] = paw[1][ks][wd];
      }
#pragma unroll
      for (int fd = 0; fd < 8; ++fd) {
        bf16x8 vb = *(const bf16x8*)((const char*)v_lds[cur] +
                                     (16 * fd + l15) * 128 + voff[ks]);
        oacc[0][fd] = mfma16(pa0.v, vb, oacc[0][fd]);
        oacc[1][fd] = mfma16(pa1.v, vb, oacc[1][fd]);
      }
    }
    __builtin_amdgcn_s_setprio(0);

    if (kt < 31) {
      asm volatile("s_waitcnt vmcnt(0)" ::: "memory");
      __builtin_amdgcn_s_barrier();
      __builtin_amdgcn_sched_barrier(0);
    }
  }

#pragma unroll
  for (int qg = 0; qg < 2; ++qg) {
    float inv[4];
#pragma unroll
    for (int r = 0; r < 4; ++r) inv[r] = 1.0f / __shfl(l_run[qg], 4 * l4 + r);
#pragma unroll
    for (int fd = 0; fd < 8; ++fd) {
      int dg = h * 128 + 16 * fd + l15;
#pragma unroll
      for (int r = 0; r < 4; ++r) {
        int qrow = qbase + qg * 16 + 4 * l4 + r;
        oat[(size_t)qrow * 4096 + dg] = f2bf(oacc[qg][fd][r] * inv[r]);
      }
    }
  }
#undef STAGE
}

// ---------------- launch ----------------
extern "C" void kernel_launch(void* const* d_in, const int* in_sizes, int n_in,
                              void* d_out, int out_size, void* d_ws, size_t ws_size,
                              hipStream_t stream) {
  const float* x = (const float*)d_in[0];
  const int* row_ids = (const int*)d_in[1];
  const int* col_ids = (const int*)d_in[2];
  const float* mask = (const float*)d_in[3];
  const float* Wq = (const float*)d_in[4];
  const float* Wk = (const float*)d_in[5];
  const float* Wv = (const float*)d_in[6];
  const float* Wo = (const float*)d_in[7];
  const float* qw = (const float*)d_in[8];
  const float* kw = (const float*)d_in[9];

  char* ws = (char*)d_ws;
  u16* xb      = (u16*)(ws);                 // [0, 16MB)   dead after gemm<0>
  u16* wqkvt   = (u16*)(ws + 16777216);      // [16, 64MB)  dead after gemm<0>
  u16* wot     = (u16*)(ws + 67108864);      // [64, 96MB)
  u16* qkbuf   = (u16*)(ws + 100663296);
  u16* vtbuf   = (u16*)(ws + 121634816);
  u16* oat     = (u16*)(ws + 125829120);
  float4* trig = (float4*)(ws + 142606336);
  int* flag    = (int*)(ws + 143654912);
  float* pbuf  = (float*)(ws);               // [0, 64MB) split-K partials (reuses xb/wqkvt)

  hipFuncSetAttribute((const void*)gemm256<0>,
                      hipFuncAttributeMaxDynamicSharedMemorySize, 131072);
  hipFuncSetAttribute((const void*)gemm256<1>,
                      hipFuncAttributeMaxDynamicSharedMemorySize, 131072);

  hipMemsetAsync(flag, 0, 4, stream);
  maskflag<<<4096, 256, 0, stream>>>((const float4*)mask, flag);
  cvt_x<<<8192, 256, 0, stream>>>((const float4*)x, (ushort4*)xb);
  tcvt<<<64 * 64, 256, 0, stream>>>(Wq, wqkvt, 4096);
  tcvt<<<64 * 16, 256, 0, stream>>>(Wk, wqkvt + (size_t)4096 * 4096, 1024);
  tcvt<<<64 * 16, 256, 0, stream>>>(Wv, wqkvt + (size_t)5120 * 4096, 1024);
  tcvt<<<64 * 64, 256, 0, stream>>>(Wo, wot, 4096);
  trig_kernel<<<256, 256, 0, stream>>>(row_ids, col_ids, trig);
  gemm256<0><<<256, 512, 114688, stream>>>(xb, wqkvt, (void*)qkbuf, vtbuf, 32);
  rope_kernel<<<2048, 256, 0, stream>>>(qkbuf, trig, qw, kw);
  attn_kernel<<<256, 512, 0, stream>>>(qkbuf, vtbuf, oat, mask, flag);
  gemm256<1><<<256, 512, 131072, stream>>>(oat, wot, (void*)pbuf, nullptr, 16);
  reduce2<<<8192, 256, 0, stream>>>((const float4*)pbuf,
                                    (const float4*)(pbuf + 8388608),
                                    (float4*)d_out);
}

// Round 8
// 346.173 us; speedup vs baseline: 1.4071x; 1.0548x over previous
//
#include <hip/hip_runtime.h>
#include <hip/hip_bf16.h>

typedef unsigned short u16;
typedef __attribute__((ext_vector_type(8))) short bf16x8;
typedef __attribute__((ext_vector_type(4))) float f32x4;

#define LOG2E_F 1.4426950408889634f
#define QSCALE (0.08838834764831845f * 7.625595228825695f * 1.4426950408889634f)

__device__ __forceinline__ u16 f2bf(float f) {
  unsigned x = __float_as_uint(f);
  unsigned r = (x + 0x7fffu + ((x >> 16) & 1u)) >> 16;  // RNE
  return (u16)r;
}
__device__ __forceinline__ float bf2f(u16 u) {
  return __uint_as_float(((unsigned)u) << 16);
}
__device__ __forceinline__ float exp2a(float x) {
  float r;
  asm("v_exp_f32 %0, %1" : "=v"(r) : "v"(x));
  return r;
}
__device__ __forceinline__ unsigned cvtpk(float lo, float hi) {
  unsigned r;
  asm("v_cvt_pk_bf16_f32 %0, %1, %2" : "=v"(r) : "v"(lo), "v"(hi));
  return r;
}

__device__ __forceinline__ void gload_lds16(const void* g, void* l) {
  __builtin_amdgcn_global_load_lds(
      (__attribute__((address_space(1))) void*)(g),
      (__attribute__((address_space(3))) void*)(l), 16, 0, 0);
}

__device__ __forceinline__ f32x4 mfma16(bf16x8 a, bf16x8 b, f32x4 c) {
  return __builtin_amdgcn_mfma_f32_16x16x32_bf16(a, b, c, 0, 0, 0);
}

// ---------------- fused prep: cvt_x + maskflag + trig ----------------
__global__ __launch_bounds__(256) void prep(const float4* __restrict__ x,
                                            ushort4* __restrict__ xb,
                                            const float4* __restrict__ mask,
                                            int* __restrict__ flag,
                                            const int* __restrict__ row_ids,
                                            const int* __restrict__ col_ids,
                                            float4* __restrict__ trig) {
  int bid = blockIdx.x;
  if (bid < 8192) {  // cvt_x: 2048x4096 f32 -> bf16
    size_t i = (size_t)bid * 256 + threadIdx.x;
    float4 v = x[i];
    ushort4 o;
    o.x = f2bf(v.x); o.y = f2bf(v.y); o.z = f2bf(v.z); o.w = f2bf(v.w);
    xb[i] = o;
  } else if (bid < 12288) {  // maskflag: 2048x2048
    size_t i = (size_t)(bid - 8192) * 256 + threadIdx.x;
    float4 v = mask[i];
    if (v.x != 0.f || v.y != 0.f || v.z != 0.f || v.w != 0.f) atomicOr(flag, 1);
  } else {  // trig: 2048 tokens x 32 freqs
    int idx = (bid - 12288) * 256 + threadIdx.x;
    int tok = idx >> 5, i = idx & 31;
    float inv = exp2f(-(float)i * 0.41524101186092030f);
    float ar = (float)row_ids[tok] * inv;
    float ac = (float)col_ids[tok] * inv * 1.618033988749895f;
    float4 o;
    o.x = cosf(ar); o.y = sinf(ar); o.z = cosf(ac); o.w = sinf(ac);
    trig[idx] = o;
  }
}

// ------ fused transpose+convert: all four weights in one dispatch ------
// W [4096][N] f32 -> Wt [N][4096] bf16
__global__ __launch_bounds__(256) void tcvt_all(const float* __restrict__ Wq,
                                                const float* __restrict__ Wk,
                                                const float* __restrict__ Wv,
                                                const float* __restrict__ Wo,
                                                u16* __restrict__ wqkvt,
                                                u16* __restrict__ wot) {
  __shared__ float t[64][65];
  int bid = blockIdx.x;
  const float* src;
  u16* dst;
  int N;
  if (bid < 4096)      { src = Wq; dst = wqkvt;                         N = 4096; }
  else if (bid < 5120) { src = Wk; dst = wqkvt + (size_t)4096 * 4096;   N = 1024; bid -= 4096; }
  else if (bid < 6144) { src = Wv; dst = wqkvt + (size_t)5120 * 4096;   N = 1024; bid -= 5120; }
  else                 { src = Wo; dst = wot;                           N = 4096; bid -= 6144; }
  int kt = bid & 63, nt = bid >> 6;
  int k0 = kt * 64, n0 = nt * 64;
  int tid = threadIdx.x;
#pragma unroll
  for (int it = 0; it < 16; ++it) {
    int idx = it * 256 + tid;
    int row = idx >> 6, col = idx & 63;
    t[row][col] = src[(size_t)(k0 + row) * N + n0 + col];
  }
  __syncthreads();
#pragma unroll
  for (int it = 0; it < 8; ++it) {
    int idx = it * 256 + tid;
    int nrow = idx >> 5, kc = idx & 31;
    ushort2 o;
    o.x = f2bf(t[kc * 2][nrow]);
    o.y = f2bf(t[kc * 2 + 1][nrow]);
    *(ushort2*)&dst[(size_t)(n0 + nrow) * 4096 + k0 + kc * 2] = o;
  }
}

// ---------------- RMSNorm + gg-RoPE (in-place on QK buffer) ----------------
__global__ __launch_bounds__(256) void rope_kernel(u16* __restrict__ qk,
                                                   const float4* __restrict__ trig,
                                                   const float* __restrict__ qw,
                                                   const float* __restrict__ kw) {
  const int tok = blockIdx.x;
  const int tid = threadIdx.x;
  const int w = tid >> 6, lane = tid & 63;
  float4 t4 = trig[tok * 32 + (lane & 31)];
  float sgn = (lane < 32) ? -1.0f : 1.0f;

  for (int it = 0; it < 10; ++it) {
    int hh = w + it * 4;
    bool isQ = (hh < 32);
    int colbase = isQ ? hh * 128 : 4096 + (hh - 32) * 128;
    const float* nw = isQ ? qw : kw;
    float scale = isQ ? QSCALE : 1.0f;
    u16* p = qk + (size_t)tok * 5120 + colbase;
    float v1 = bf2f(p[lane]);
    float v2 = bf2f(p[64 + lane]);
    float w1 = nw[lane], w2 = nw[64 + lane];
    float ss = v1 * v1 + v2 * v2;
    ss += __shfl_xor(ss, 1);  ss += __shfl_xor(ss, 2);  ss += __shfl_xor(ss, 4);
    ss += __shfl_xor(ss, 8);  ss += __shfl_xor(ss, 16); ss += __shfl_xor(ss, 32);
    float rinv = rsqrtf(ss * (1.0f / 128.0f) + 1e-6f);
    float n1 = v1 * rinv * w1;
    float n2 = v2 * rinv * w2;
    float p1 = __shfl_xor(n1, 32);
    float p2 = __shfl_xor(n2, 32);
    float r1 = n1 * t4.x + sgn * p1 * t4.y;
    float r2 = n2 * t4.z + sgn * p2 * t4.w;
    p[lane]      = f2bf(r1 * scale);
    p[64 + lane] = f2bf(r2 * scale);
  }
}

// ======== 256-wide 8-phase GEMM: C[M][N] = A[M][4096] * Bt[N][4096]^T ========
// MODE 0: BM=256, BN=192 -> grid 8x32=256 (1/CU). Out: qk bf16 / Vt transposed.
// MODE 1: BM=256, BN=256, split-K=2 -> grid 2x128=256 (1/CU). Out: f32 partials.
template <int MODE>
__global__ __launch_bounds__(512, 2) void gemm256(const u16* __restrict__ A,
                                                  const u16* __restrict__ Bt,
                                                  void* __restrict__ C0,
                                                  u16* __restrict__ Vt, int nnt) {
  extern __shared__ char smem[];
  const int tid = threadIdx.x, lane = tid & 63, w = tid >> 6;
  const int l15 = lane & 15, l4 = lane >> 4;
  const int wr = w >> 2, wc = w & 3;
  constexpr int NF = (MODE == 0) ? 3 : 4;
  constexpr int BNW = (MODE == 0) ? 48 : 64;

  int wgid = (blockIdx.x & 7) * (gridDim.x >> 3) + (blockIdx.x >> 3);
  int kh = 0;
  if (MODE == 1) { kh = wgid >> 7; wgid &= 127; }
  const int mt = wgid / nnt, nt = wgid % nnt;
  const int m0 = mt * 256;
  const int n0 = nt * ((MODE == 0) ? 192 : 256);
  const int tbase = kh * 32;

  const int kswz = (((tid & 7) ^ ((tid >> 3) & 7)) << 4);
  const char* arow = (const char*)A + (size_t)(m0 + (tid >> 3)) * 8192 + kswz;
  const char* brow = (const char*)Bt + (size_t)(n0 + (tid >> 3)) * 8192 + kswz;

  auto stageA = [&](int t, int h) {
#pragma unroll
    for (int rd = 0; rd < 2; ++rd)
      gload_lds16(arow + (size_t)(h * 128 + rd * 64) * 8192 + t * 128,
                  smem + ((t & 1) * 2 + h) * 16384 + rd * 8192 + w * 1024);
  };
  auto stageB0 = [&](int t) {
#pragma unroll
    for (int rd = 0; rd < 3; ++rd)
      gload_lds16(brow + (size_t)(rd * 64) * 8192 + t * 128,
                  smem + 65536 + (t & 1) * 24576 + rd * 8192 + w * 1024);
  };
  auto stageB1 = [&](int t, int h) {
#pragma unroll
    for (int rd = 0; rd < 2; ++rd)
      gload_lds16(brow + (size_t)(h * 128 + rd * 64) * 8192 + t * 128,
                  smem + 65536 + ((t & 1) * 2 + h) * 16384 + rd * 8192 + w * 1024);
  };

  f32x4 acc[8][NF];
#pragma unroll
  for (int i = 0; i < 8; ++i)
#pragma unroll
    for (int j = 0; j < NF; ++j) acc[i][j] = (f32x4){0.f, 0.f, 0.f, 0.f};

  const int aoff0 = ((l4) ^ (l15 & 7)) << 4;
  const int aoff1 = ((4 + l4) ^ (l15 & 7)) << 4;

  stageA(tbase, 0); stageA(tbase, 1);
  if constexpr (MODE == 0) {
    stageB0(tbase); stageB0(tbase + 1);
    asm volatile("s_waitcnt vmcnt(3)" ::: "memory");
  } else {
    stageB1(tbase, 0); stageB1(tbase, 1);
    stageB1(tbase + 1, 0); stageB1(tbase + 1, 1);
    asm volatile("s_waitcnt vmcnt(4)" ::: "memory");
  }
  __builtin_amdgcn_s_barrier();

  auto do_iter = [&](int t0, int last) {
    bf16x8 bfr[NF][2];
#pragma unroll
    for (int p = 0; p < 8; ++p) {
      const int s = p >> 2, qd = p & 3;
      const char* aT = smem + (s * 2 + wr) * 16384 + l15 * 128;
      bf16x8 afr[2][2];
#pragma unroll
      for (int jm = 0; jm < 2; ++jm) {
        afr[jm][0] = *(const bf16x8*)(aT + (2 * qd + jm) * 2048 + aoff0);
        afr[jm][1] = *(const bf16x8*)(aT + (2 * qd + jm) * 2048 + aoff1);
      }
      if (qd == 0) {
        const char* bT;
        if constexpr (MODE == 0)
          bT = smem + 65536 + s * 24576 + (wc * 48 + l15) * 128;
        else
          bT = smem + 65536 + (s * 2 + (wc >> 1)) * 16384 +
               ((wc & 1) * 64 + l15) * 128;
#pragma unroll
        for (int nf = 0; nf < NF; ++nf) {
          bfr[nf][0] = *(const bf16x8*)(bT + nf * 2048 + aoff0);
          bfr[nf][1] = *(const bf16x8*)(bT + nf * 2048 + aoff1);
        }
      }
      if (p == 0) { stageA(t0 + 1, 0); stageA(t0 + 1, 1); }
      if (!last) {
        if constexpr (MODE == 0) {
          if (p == 1) stageB0(t0 + 2);
          if (p == 5) stageB0(t0 + 3);
        } else {
          if (p == 1) stageB1(t0 + 2, 0);
          if (p == 2) stageB1(t0 + 2, 1);
          if (p == 5) stageB1(t0 + 3, 0);
          if (p == 6) stageB1(t0 + 3, 1);
        }
        if (p == 4) { stageA(t0 + 2, 0); stageA(t0 + 2, 1); }
      }
      if (p == 3) {
        if (last) asm volatile("s_waitcnt vmcnt(0)" ::: "memory");
        else if constexpr (MODE == 0)
          asm volatile("s_waitcnt vmcnt(3)" ::: "memory");
        else
          asm volatile("s_waitcnt vmcnt(4)" ::: "memory");
      }
      if (p == 7 && !last) {
        if constexpr (MODE == 0)
          asm volatile("s_waitcnt vmcnt(3)" ::: "memory");
        else
          asm volatile("s_waitcnt vmcnt(4)" ::: "memory");
      }
      __builtin_amdgcn_s_barrier();
      asm volatile("s_waitcnt lgkmcnt(0)" ::: "memory");
      __builtin_amdgcn_sched_barrier(0);
      __builtin_amdgcn_s_setprio(1);
#pragma unroll
      for (int ks = 0; ks < 2; ++ks)
#pragma unroll
        for (int jm = 0; jm < 2; ++jm)
#pragma unroll
          for (int nf = 0; nf < NF; ++nf)
            acc[2 * qd + jm][nf] =
                mfma16(afr[jm][ks], bfr[nf][ks], acc[2 * qd + jm][nf]);
      __builtin_amdgcn_s_setprio(0);
      __builtin_amdgcn_s_barrier();
    }
  };

  constexpr int NIT = (MODE == 0) ? 32 : 16;
  for (int j = 0; j < NIT - 1; ++j) do_iter(tbase + 2 * j, 0);
  do_iter(tbase + 2 * (NIT - 1), 1);

  if (MODE == 0) {
    u16* qkp = (u16*)C0;
#pragma unroll
    for (int mf = 0; mf < 8; ++mf)
#pragma unroll
      for (int nf = 0; nf < NF; ++nf) {
        int ng = n0 + wc * BNW + nf * 16 + l15;
        if (ng < 5120) {
#pragma unroll
          for (int r = 0; r < 4; ++r) {
            int mg = m0 + wr * 128 + mf * 16 + l4 * 4 + r;
            qkp[(size_t)mg * 5120 + ng] = f2bf(acc[mf][nf][r]);
          }
        } else {
          int vr = ng - 5120;
          int mg = m0 + wr * 128 + mf * 16 + l4 * 4;
          ushort4 pk;
          pk.x = f2bf(acc[mf][nf][0]); pk.y = f2bf(acc[mf][nf][1]);
          pk.z = f2bf(acc[mf][nf][2]); pk.w = f2bf(acc[mf][nf][3]);
          *(ushort4*)&Vt[(size_t)vr * 2048 + mg] = pk;
        }
      }
  } else {
    float* Cp = (float*)C0 + (size_t)kh * 8388608;
#pragma unroll
    for (int mf = 0; mf < 8; ++mf)
#pragma unroll
      for (int nf = 0; nf < NF; ++nf) {
        int ng = n0 + wc * BNW + nf * 16 + l15;
#pragma unroll
        for (int r = 0; r < 4; ++r) {
          int mg = m0 + wr * 128 + mf * 16 + l4 * 4 + r;
          Cp[(size_t)mg * 4096 + ng] = acc[mf][nf][r];
        }
      }
  }
}

// ---------------- split-K reduce: out = p0 + p1 ----------------
__global__ __launch_bounds__(256) void reduce2(const float4* __restrict__ p0,
                                               const float4* __restrict__ p1,
                                               float4* __restrict__ out) {
  size_t i = (size_t)blockIdx.x * 256 + threadIdx.x;
  float4 a = p0[i], b = p1[i];
  float4 o;
  o.x = a.x + b.x; o.y = a.y + b.y; o.z = a.z + b.z; o.w = a.w + b.w;
  out[i] = o;
}

// ---------------- GQA flash attention (4 waves x 32q, 2 blocks/CU) ----------------
// qk: [2048][5120] bf16 (post-rope, Q pre-scaled); vt: [1024][2048] bf16;
// oat: [2048][4096] bf16. Block: 4 waves x 32 q = 128 q rows, 256 thr.
// Grid 512 (16 qt x 32 heads) -> 2 independent barrier-groups per CU.
__global__ __launch_bounds__(256, 2) void attn_kernel(const u16* __restrict__ qk,
                                                      const u16* __restrict__ vt,
                                                      u16* __restrict__ oat,
                                                      const float* __restrict__ mask,
                                                      const int* __restrict__ flag) {
  __shared__ u16 k_lds[2][64 * 128];  // [kv][d], 256B rows, chunk^(row&15)
  __shared__ u16 v_lds[2][64 * 128];  // [d=128][kv=64], 128B rows, chunk^(row&7)

  const int tid = threadIdx.x, lane = tid & 63, w = tid >> 6;
  const int l15 = lane & 15, l4 = lane >> 4;
  const int bid = blockIdx.x;
  const int hk = bid & 7;          // XCD-pinned kv head
  const int rest = bid >> 3;       // 0..63
  const int h = hk * 4 + (rest & 3);
  const int qt = rest >> 2;        // 0..15
  const int qbase = qt * 128 + w * 32;

  const bool use_mask = (*flag != 0);
  const char* kbase = (const char*)qk + 8192 + (size_t)hk * 256;
  const char* vbase = (const char*)vt + (size_t)hk * 128 * 4096;

  bf16x8 qf[2][4];
#pragma unroll
  for (int qg = 0; qg < 2; ++qg) {
    const char* qp = (const char*)qk +
                     (size_t)(qbase + qg * 16 + l15) * 10240 + h * 256 + l4 * 16;
#pragma unroll
    for (int ks = 0; ks < 4; ++ks) qf[qg][ks] = *(const bf16x8*)(qp + ks * 64);
  }

  f32x4 oacc[2][8];
#pragma unroll
  for (int qg = 0; qg < 2; ++qg)
#pragma unroll
    for (int fd = 0; fd < 8; ++fd) oacc[qg][fd] = (f32x4){0.f, 0.f, 0.f, 0.f};
  float m_run[2] = {-1e30f, -1e30f};
  float l_run[2] = {0.f, 0.f};

  int koff[4], voff[2];
#pragma unroll
  for (int ks = 0; ks < 4; ++ks) koff[ks] = ((4 * ks + l4) ^ l15) << 4;
#pragma unroll
  for (int ks = 0; ks < 2; ++ks) voff[ks] = ((4 * ks + l4) ^ (l15 & 7)) << 4;

  // 256-thread staging: K 1024 chunks (16/row), V 1024 chunks (8/row)
#define STAGE(buf, kv0)                                                        \
  {                                                                            \
    _Pragma("unroll") for (int rd = 0; rd < 4; ++rd) {                         \
      int c = rd * 256 + tid;                                                  \
      int row = c >> 4;                                                        \
      int src = ((c & 15) ^ (row & 15)) << 4;                                  \
      gload_lds16(kbase + (size_t)((kv0) + row) * 10240 + src,                 \
                  (char*)k_lds[buf] + (rd * 256 + w * 64) * 16);               \
      int rowv = c >> 3;                                                       \
      int srcv = ((c & 7) ^ (rowv & 7)) << 4;                                  \
      gload_lds16(vbase + (size_t)rowv * 4096 + (kv0) * 2 + srcv,              \
                  (char*)v_lds[buf] + (rd * 256 + w * 64) * 16);               \
    }                                                                          \
  }

  STAGE(0, 0);
  asm volatile("s_waitcnt vmcnt(0)" ::: "memory");
  __builtin_amdgcn_s_barrier();
  __builtin_amdgcn_sched_barrier(0);

  for (int kt = 0; kt < 32; ++kt) {
    const int cur = kt & 1;
    const int kv0 = kt * 64;
    if (kt < 31) STAGE(cur ^ 1, kv0 + 64);

    f32x4 sA[2][4];
#pragma unroll
    for (int qg = 0; qg < 2; ++qg)
#pragma unroll
      for (int f = 0; f < 4; ++f) sA[qg][f] = (f32x4){0.f, 0.f, 0.f, 0.f};

    __builtin_amdgcn_s_setprio(1);
#pragma unroll
    for (int ks = 0; ks < 4; ++ks) {
      bf16x8 kfr[4];
#pragma unroll
      for (int f = 0; f < 4; ++f)
        kfr[f] = *(const bf16x8*)((const char*)k_lds[cur] +
                                  (16 * f + l15) * 256 + koff[ks]);
#pragma unroll
      for (int f = 0; f < 4; ++f) {
        sA[0][f] = mfma16(kfr[f], qf[0][ks], sA[0][f]);
        sA[1][f] = mfma16(kfr[f], qf[1][ks], sA[1][f]);
      }
    }
    __builtin_amdgcn_s_setprio(0);

    if (use_mask) {
#pragma unroll
      for (int qg = 0; qg < 2; ++qg) {
        int qglob = qbase + qg * 16 + l15;
#pragma unroll
        for (int f = 0; f < 4; ++f)
#pragma unroll
          for (int r = 0; r < 4; ++r) {
            int kvglob = kv0 + 16 * f + 4 * l4 + r;
            sA[qg][f][r] += LOG2E_F * mask[(size_t)qglob * 2048 + kvglob];
          }
      }
    }

    unsigned paw[2][2][4];
#pragma unroll
    for (int qg = 0; qg < 2; ++qg) {
      float mx = fmaxf(fmaxf(fmaxf(sA[qg][0][0], sA[qg][0][1]),
                             fmaxf(sA[qg][0][2], sA[qg][0][3])),
                       fmaxf(fmaxf(sA[qg][1][0], sA[qg][1][1]),
                             fmaxf(sA[qg][1][2], sA[qg][1][3])));
      float mx2 = fmaxf(fmaxf(fmaxf(sA[qg][2][0], sA[qg][2][1]),
                              fmaxf(sA[qg][2][2], sA[qg][2][3])),
                        fmaxf(fmaxf(sA[qg][3][0], sA[qg][3][1]),
                              fmaxf(sA[qg][3][2], sA[qg][3][3])));
      mx = fmaxf(mx, mx2);
      mx = fmaxf(mx, __shfl_xor(mx, 16));
      mx = fmaxf(mx, __shfl_xor(mx, 32));
      if (__any(mx > m_run[qg] + 8.0f)) {
        float mnew = fmaxf(m_run[qg], mx);
        float a = exp2a(m_run[qg] - mnew);
        l_run[qg] *= a;
        m_run[qg] = mnew;
        float a0 = __shfl(a, 4 * l4 + 0);
        float a1 = __shfl(a, 4 * l4 + 1);
        float a2 = __shfl(a, 4 * l4 + 2);
        float a3 = __shfl(a, 4 * l4 + 3);
#pragma unroll
        for (int fd = 0; fd < 8; ++fd) {
          oacc[qg][fd][0] *= a0; oacc[qg][fd][1] *= a1;
          oacc[qg][fd][2] *= a2; oacc[qg][fd][3] *= a3;
        }
      }
      float ps = 0.f;
      unsigned W[4][2];
#pragma unroll
      for (int f = 0; f < 4; ++f) {
        float p0 = exp2a(sA[qg][f][0] - m_run[qg]);
        float p1 = exp2a(sA[qg][f][1] - m_run[qg]);
        float p2 = exp2a(sA[qg][f][2] - m_run[qg]);
        float p3 = exp2a(sA[qg][f][3] - m_run[qg]);
        ps += (p0 + p1) + (p2 + p3);
        W[f][0] = cvtpk(p0, p1);
        W[f][1] = cvtpk(p2, p3);
      }
      ps += __shfl_xor(ps, 16);
      ps += __shfl_xor(ps, 32);
      l_run[qg] += ps;
#pragma unroll
      for (int ks = 0; ks < 2; ++ks)
#pragma unroll
        for (int wd = 0; wd < 4; ++wd) {
          int src = l15 + 16 * (2 * (l4 & 1) + (wd >> 1));
          unsigned v0 = (unsigned)__shfl((int)W[2 * ks][wd & 1], src);
          unsigned v1 = (unsigned)__shfl((int)W[2 * ks + 1][wd & 1], src);
          paw[qg][ks][wd] = (l4 & 2) ? v1 : v0;
        }
    }

    __builtin_amdgcn_s_setprio(1);
#pragma unroll
    for (int ks = 0; ks < 2; ++ks) {
      union { unsigned u[4]; bf16x8 v; } pa0, pa1;
#pragma unroll
      for (int wd = 0; wd < 4; ++wd) {
        pa0.u[wd] = paw[0][ks][wd];
        pa1.u[wd] = paw[1][ks][wd];
      }
#pragma unroll
      for (int fd = 0; fd < 8; ++fd) {
        bf16x8 vb = *(const bf16x8*)((const char*)v_lds[cur] +
                                     (16 * fd + l15) * 128 + voff[ks]);
        oacc[0][fd] = mfma16(pa0.v, vb, oacc[0][fd]);
        oacc[1][fd] = mfma16(pa1.v, vb, oacc[1][fd]);
      }
    }
    __builtin_amdgcn_s_setprio(0);

    if (kt < 31) {
      asm volatile("s_waitcnt vmcnt(0)" ::: "memory");
      __builtin_amdgcn_s_barrier();
      __builtin_amdgcn_sched_barrier(0);
    }
  }

#pragma unroll
  for (int qg = 0; qg < 2; ++qg) {
    float inv[4];
#pragma unroll
    for (int r = 0; r < 4; ++r) inv[r] = 1.0f / __shfl(l_run[qg], 4 * l4 + r);
#pragma unroll
    for (int fd = 0; fd < 8; ++fd) {
      int dg = h * 128 + 16 * fd + l15;
#pragma unroll
      for (int r = 0; r < 4; ++r) {
        int qrow = qbase + qg * 16 + 4 * l4 + r;
        oat[(size_t)qrow * 4096 + dg] = f2bf(oacc[qg][fd][r] * inv[r]);
      }
    }
  }
#undef STAGE
}

// ---------------- launch ----------------
extern "C" void kernel_launch(void* const* d_in, const int* in_sizes, int n_in,
                              void* d_out, int out_size, void* d_ws, size_t ws_size,
                              hipStream_t stream) {
  const float* x = (const float*)d_in[0];
  const int* row_ids = (const int*)d_in[1];
  const int* col_ids = (const int*)d_in[2];
  const float* mask = (const float*)d_in[3];
  const float* Wq = (const float*)d_in[4];
  const float* Wk = (const float*)d_in[5];
  const float* Wv = (const float*)d_in[6];
  const float* Wo = (const float*)d_in[7];
  const float* qw = (const float*)d_in[8];
  const float* kw = (const float*)d_in[9];

  char* ws = (char*)d_ws;
  u16* xb      = (u16*)(ws);                 // [0, 16MB)   dead after gemm<0>
  u16* wqkvt   = (u16*)(ws + 16777216);      // [16, 64MB)  dead after gemm<0>
  u16* wot     = (u16*)(ws + 67108864);      // [64, 96MB)
  u16* qkbuf   = (u16*)(ws + 100663296);
  u16* vtbuf   = (u16*)(ws + 121634816);
  u16* oat     = (u16*)(ws + 125829120);
  float4* trig = (float4*)(ws + 142606336);
  int* flag    = (int*)(ws + 143654912);
  float* pbuf  = (float*)(ws);               // [0, 64MB) split-K partials

  hipFuncSetAttribute((const void*)gemm256<0>,
                      hipFuncAttributeMaxDynamicSharedMemorySize, 131072);
  hipFuncSetAttribute((const void*)gemm256<1>,
                      hipFuncAttributeMaxDynamicSharedMemorySize, 131072);

  hipMemsetAsync(flag, 0, 4, stream);
  prep<<<12544, 256, 0, stream>>>((const float4*)x, (ushort4*)xb,
                                  (const float4*)mask, flag, row_ids, col_ids,
                                  trig);
  tcvt_all<<<10240, 256, 0, stream>>>(Wq, Wk, Wv, Wo, wqkvt, wot);
  gemm256<0><<<256, 512, 114688, stream>>>(xb, wqkvt, (void*)qkbuf, vtbuf, 32);
  rope_kernel<<<2048, 256, 0, stream>>>(qkbuf, trig, qw, kw);
  attn_kernel<<<512, 256, 0, stream>>>(qkbuf, vtbuf, oat, mask, flag);
  gemm256<1><<<256, 512, 131072, stream>>>(oat, wot, (void*)pbuf, nullptr, 16);
  reduce2<<<8192, 256, 0, stream>>>((const float4*)pbuf,
                                    (const float4*)(pbuf + 8388608),
                                    (float4*)d_out);
}